// Round 1
// baseline (1553.417 us; speedup 1.0000x reference)
//
#include <hip/hip_runtime.h>
#include <stdint.h>

typedef unsigned short ushort_t;
typedef __attribute__((ext_vector_type(4))) float f32x4;
typedef __attribute__((ext_vector_type(8))) short short8;

#define L_SEQ   2048
#define NROWS   8192          // B*L = 4*2048
#define KDIM    1024
#define DINNER  2048
#define NHEADS  32
#define DSTATE  64
#define DCONVD  2176          // D_INNER + 2*D_STATE
#define NPROJ   4256
#define NPROJP  4352          // padded to 34*128
#define LDZX    4352

__device__ __forceinline__ float bf2f(ushort_t u) {
    union { uint32_t i; float f; } v; v.i = ((uint32_t)u) << 16; return v.f;
}
__device__ __forceinline__ ushort_t f2bf(float f) {
    uint32_t x = __float_as_uint(f);
    x += 0x7FFFu + ((x >> 16) & 1u);
    return (ushort_t)(x >> 16);
}

// ---------------- cast kernels ----------------
__global__ __launch_bounds__(256) void cast_bf16_kernel(const float* __restrict__ in,
                                                        ushort_t* __restrict__ out, int n4) {
    int i = blockIdx.x * 256 + threadIdx.x;
    if (i >= n4) return;
    float4 v = ((const float4*)in)[i];
    ushort4 o;
    o.x = f2bf(v.x); o.y = f2bf(v.y); o.z = f2bf(v.z); o.w = f2bf(v.w);
    ((ushort4*)out)[i] = o;
}

// in_proj_w (4256,1024) -> bf16 padded to (4352,1024), pad rows = 0
__global__ __launch_bounds__(256) void cast_pad_w_kernel(const float* __restrict__ w,
                                                         ushort_t* __restrict__ out) {
    int i = blockIdx.x * 256 + threadIdx.x;   // group of 4 elems
    int idx = i * 4;
    int row = idx >> 10;
    ushort4 o;
    if (row < NPROJ) {
        float4 v = ((const float4*)w)[i];
        o.x = f2bf(v.x); o.y = f2bf(v.y); o.z = f2bf(v.z); o.w = f2bf(v.w);
    } else {
        o.x = 0; o.y = 0; o.z = 0; o.w = 0;
    }
    ((ushort4*)out)[i] = o;
}

// ---------------- MFMA GEMM:  C[M][N] = A[M][K] * B[N][K]^T ----------------
__device__ __forceinline__ void async16(const void* g, void* l) {
    __builtin_amdgcn_global_load_lds((const __attribute__((address_space(1))) void*)g,
                                     (__attribute__((address_space(3))) void*)l, 16, 0, 0);
}

template<bool OUT_BF16>
__global__ __launch_bounds__(256) void gemm_bt_kernel(const ushort_t* __restrict__ A,
                                                      const ushort_t* __restrict__ B,
                                                      void* __restrict__ Cp,
                                                      const int K, const int ldc) {
    __shared__ ushort_t As[4096];   // [128][32] bf16
    __shared__ ushort_t Bs[4096];
    const int tid  = threadIdx.x;
    const int wave = tid >> 6;
    const int lane = tid & 63;
    const int llo  = lane & 15;
    const int lhi  = lane >> 4;
    const int m0 = blockIdx.y * 128;
    const int n0 = blockIdx.x * 128;
    const int wr = wave >> 1, wc = wave & 1;

    f32x4 acc[4][4];
    const f32x4 zero = {0.f, 0.f, 0.f, 0.f};
#pragma unroll
    for (int i = 0; i < 4; ++i)
#pragma unroll
        for (int j = 0; j < 4; ++j) acc[i][j] = zero;

    const int srow = tid >> 2;      // staging row (round r adds 64)
    const int skq  = tid & 3;
    const ushort_t* gA = A + (size_t)(m0 + srow) * K + skq * 8;
    const ushort_t* gB = B + (size_t)(n0 + srow) * K + skq * 8;
    ushort_t* lA0 = As + wave * 512;
    ushort_t* lA1 = As + 2048 + wave * 512;
    ushort_t* lB0 = Bs + wave * 512;
    ushort_t* lB1 = Bs + 2048 + wave * 512;
    const size_t rstep = (size_t)64 * K;

    const ushort_t* pa = As + (wr * 64 + llo) * 32 + lhi * 8;
    const ushort_t* pb = Bs + (wc * 64 + llo) * 32 + lhi * 8;

    for (int k0 = 0; k0 < K; k0 += 32) {
        __syncthreads();
        async16(gA + k0, lA0);
        async16(gA + rstep + k0, lA1);
        async16(gB + k0, lB0);
        async16(gB + rstep + k0, lB1);
        __syncthreads();
        short8 af[4], bfr[4];
#pragma unroll
        for (int i = 0; i < 4; ++i) af[i]  = *(const short8*)(pa + i * 512);
#pragma unroll
        for (int j = 0; j < 4; ++j) bfr[j] = *(const short8*)(pb + j * 512);
#pragma unroll
        for (int i = 0; i < 4; ++i)
#pragma unroll
            for (int j = 0; j < 4; ++j)
                acc[i][j] = __builtin_amdgcn_mfma_f32_16x16x32_bf16(af[i], bfr[j], acc[i][j], 0, 0, 0);
    }

#pragma unroll
    for (int i = 0; i < 4; ++i)
#pragma unroll
        for (int j = 0; j < 4; ++j) {
            const int col = n0 + wc * 64 + j * 16 + llo;
            const int rowb = m0 + wr * 64 + i * 16 + lhi * 4;
#pragma unroll
            for (int r = 0; r < 4; ++r) {
                if (OUT_BF16) {
                    ((ushort_t*)Cp)[(size_t)(rowb + r) * ldc + col] = f2bf(acc[i][j][r]);
                } else {
                    ((float*)Cp)[(size_t)(rowb + r) * ldc + col] = acc[i][j][r];
                }
            }
        }
}

// ---------------- conv (4-tap causal) + SiLU ----------------
__global__ __launch_bounds__(256) void conv_silu_kernel(const ushort_t* __restrict__ zx,
                                                        const float* __restrict__ conv_w,
                                                        const float* __restrict__ conv_b,
                                                        ushort_t* __restrict__ convout) {
    const int c = blockIdx.x * 256 + threadIdx.x;
    const int row = blockIdx.y;
    if (c >= DCONVD) return;
    const int l = row & (L_SEQ - 1);
    float acc = conv_b[c];
#pragma unroll
    for (int k = 0; k < 4; ++k) {
        int ll = l - 3 + k;
        if (ll >= 0)
            acc += bf2f(zx[(size_t)(row - 3 + k) * LDZX + DINNER + c]) * conv_w[c * 4 + k];
    }
    float s = acc / (1.f + expf(-acc));
    convout[(size_t)row * DCONVD + c] = f2bf(s);
}

// ---------------- dt = softplus(raw + bias) ----------------
__global__ __launch_bounds__(256) void dt_kernel(const ushort_t* __restrict__ zx,
                                                 const float* __restrict__ dt_bias,
                                                 float* __restrict__ dtb) {
    int idx = blockIdx.x * 256 + threadIdx.x;   // NROWS*32
    int row = idx >> 5;
    int h = idx & 31;
    float v = bf2f(zx[(size_t)row * LDZX + NPROJ - NHEADS + h]) + dt_bias[h];
    dtb[idx] = (v > 20.f) ? v : log1pf(expf(v));
}

// ---------------- sequential SSM scan, one WG per (b,h) ----------------
__global__ __launch_bounds__(256) void scan_kernel(const ushort_t* __restrict__ conv,
                                                   const float* __restrict__ dtb,
                                                   const float* __restrict__ A_log,
                                                   const float* __restrict__ Dvec,
                                                   ushort_t* __restrict__ ybuf) {
    const int h = blockIdx.x;
    const int b = blockIdx.y;
    const int tid = threadIdx.x;
    const int p = tid >> 2;        // 0..63 headdim
    const int q = tid & 3;         // 4-way split of dstate
    const float A  = -expf(A_log[h]);
    const float Dh = Dvec[h];

    __shared__ __align__(16) float sB[2][64];
    __shared__ __align__(16) float sC[2][64];
    __shared__ __align__(16) float sX[2][64];
    __shared__ float sdt[2];

    float hst[16];
#pragma unroll
    for (int i = 0; i < 16; ++i) hst[i] = 0.f;

    const size_t baserow = (size_t)b * L_SEQ;

    { // stage t = 0 into buffer 0
        size_t row = baserow;
        if (tid < 64)       sB[0][tid]       = bf2f(conv[row * DCONVD + DINNER + tid]);
        else if (tid < 128) sC[0][tid - 64]  = bf2f(conv[row * DCONVD + DINNER + DSTATE + (tid - 64)]);
        else if (tid < 192) sX[0][tid - 128] = bf2f(conv[row * DCONVD + (size_t)h * 64 + (tid - 128)]);
        else if (tid == 192) sdt[0] = dtb[row * NHEADS + h];
    }
    __syncthreads();

    for (int t = 0; t < L_SEQ; ++t) {
        const int cur = t & 1, nxt = cur ^ 1;
        // prefetch t+1 into registers
        float pf = 0.f;
        const bool havepf = (t + 1 < L_SEQ);
        if (havepf) {
            size_t row = baserow + t + 1;
            if (tid < 64)       pf = bf2f(conv[row * DCONVD + DINNER + tid]);
            else if (tid < 128) pf = bf2f(conv[row * DCONVD + DINNER + DSTATE + (tid - 64)]);
            else if (tid < 192) pf = bf2f(conv[row * DCONVD + (size_t)h * 64 + (tid - 128)]);
            else if (tid == 192) pf = dtb[row * NHEADS + h];
        }
        // compute step t
        const float dt_t = sdt[cur];
        const float dA = __expf(dt_t * A);
        const float xv = sX[cur][p];
        const float kk = dt_t * xv;
        float ysum = 0.f;
        const float4* B4 = (const float4*)&sB[cur][0];
        const float4* C4 = (const float4*)&sC[cur][0];
#pragma unroll
        for (int ii = 0; ii < 4; ++ii) {
            const float4 bb = B4[q * 4 + ii];
            const float4 cc = C4[q * 4 + ii];
            float* hp = &hst[ii * 4];
            hp[0] = hp[0] * dA + kk * bb.x; ysum += hp[0] * cc.x;
            hp[1] = hp[1] * dA + kk * bb.y; ysum += hp[1] * cc.y;
            hp[2] = hp[2] * dA + kk * bb.z; ysum += hp[2] * cc.z;
            hp[3] = hp[3] * dA + kk * bb.w; ysum += hp[3] * cc.w;
        }
        ysum += __shfl_xor(ysum, 1);
        ysum += __shfl_xor(ysum, 2);
        if (q == 0)
            ybuf[(baserow + t) * DINNER + (size_t)h * 64 + p] = f2bf(ysum + Dh * xv);
        // write prefetch into other buffer
        if (havepf) {
            if (tid < 64)       sB[nxt][tid]       = pf;
            else if (tid < 128) sC[nxt][tid - 64]  = pf;
            else if (tid < 192) sX[nxt][tid - 128] = pf;
            else if (tid == 192) sdt[nxt] = pf;
        }
        __syncthreads();
    }
}

// ---------------- gate (y * silu(z)) + RMSNorm -> bf16 ----------------
__global__ __launch_bounds__(256) void gatenorm_kernel(const ushort_t* __restrict__ ybuf,
                                                       const ushort_t* __restrict__ zx,
                                                       const float* __restrict__ norm_w,
                                                       ushort_t* __restrict__ gbuf) {
    const int row = blockIdx.x;
    const int tid = threadIdx.x;
    short8 yv = *(const short8*)(ybuf + (size_t)row * DINNER + tid * 8);
    short8 zv = *(const short8*)(zx + (size_t)row * LDZX + tid * 8);
    float g[8];
    float ss = 0.f;
#pragma unroll
    for (int i = 0; i < 8; ++i) {
        float y = bf2f((ushort_t)yv[i]);
        float z = bf2f((ushort_t)zv[i]);
        float sz = z / (1.f + expf(-z));
        float gg = y * sz;
        g[i] = gg;
        ss += gg * gg;
    }
#pragma unroll
    for (int o = 32; o > 0; o >>= 1) ss += __shfl_xor(ss, o);
    __shared__ float wsum[4];
    if ((tid & 63) == 0) wsum[tid >> 6] = ss;
    __syncthreads();
    float tot = wsum[0] + wsum[1] + wsum[2] + wsum[3];
    float scale = rsqrtf(tot * (1.0f / (float)DINNER) + 1e-5f);
    short8 o8;
#pragma unroll
    for (int i = 0; i < 8; ++i)
        o8[i] = (short)f2bf(g[i] * scale * norm_w[tid * 8 + i]);
    *(short8*)(gbuf + (size_t)row * DINNER + tid * 8) = o8;
}

// ---------------- launch ----------------
extern "C" void kernel_launch(void* const* d_in, const int* in_sizes, int n_in,
                              void* d_out, int out_size, void* d_ws, size_t ws_size,
                              hipStream_t stream) {
    const float* x          = (const float*)d_in[0];
    const float* in_proj_w  = (const float*)d_in[1];
    const float* conv_w     = (const float*)d_in[2];
    const float* conv_b     = (const float*)d_in[3];
    const float* dt_bias    = (const float*)d_in[4];
    const float* A_log      = (const float*)d_in[5];
    const float* Dvec       = (const float*)d_in[6];
    const float* norm_w     = (const float*)d_in[7];
    const float* out_proj_w = (const float*)d_in[8];
    float* out = (float*)d_out;

    char* ws = (char*)d_ws;
    size_t off = 0;
    ushort_t* xbf  = (ushort_t*)(ws + off); off += (size_t)NROWS * KDIM * 2;        // 16.8 MB
    ushort_t* wbf  = (ushort_t*)(ws + off); off += (size_t)NPROJP * KDIM * 2;       // 8.9 MB
    ushort_t* owbf = (ushort_t*)(ws + off); off += (size_t)KDIM * DINNER * 2;       // 4.2 MB
    ushort_t* zx   = (ushort_t*)(ws + off); off += (size_t)NROWS * LDZX * 2;        // 71.3 MB
    ushort_t* cvb  = (ushort_t*)(ws + off); off += (size_t)NROWS * DCONVD * 2;      // 35.7 MB
    float*    dtb  = (float*)(ws + off);    off += (size_t)NROWS * NHEADS * 4;      // 1.05 MB
    ushort_t* ybuf = (ushort_t*)(ws + off); off += (size_t)NROWS * DINNER * 2;      // 33.6 MB
    ushort_t* gbuf = (ushort_t*)(ws + off); off += (size_t)NROWS * DINNER * 2;      // 33.6 MB

    // casts
    cast_bf16_kernel<<<8192, 256, 0, stream>>>(x, xbf, NROWS * KDIM / 4);
    cast_pad_w_kernel<<<4352, 256, 0, stream>>>(in_proj_w, wbf);
    cast_bf16_kernel<<<2048, 256, 0, stream>>>(out_proj_w, owbf, KDIM * DINNER / 4);

    // in-proj GEMM: zx[8192][4352] (bf16)
    gemm_bt_kernel<true><<<dim3(NPROJP / 128, NROWS / 128), 256, 0, stream>>>(
        xbf, wbf, zx, KDIM, LDZX);

    // conv + silu
    conv_silu_kernel<<<dim3((DCONVD + 255) / 256, NROWS), 256, 0, stream>>>(zx, conv_w, conv_b, cvb);

    // dt
    dt_kernel<<<NROWS * NHEADS / 256, 256, 0, stream>>>(zx, dt_bias, dtb);

    // scan
    scan_kernel<<<dim3(NHEADS, 4), 256, 0, stream>>>(cvb, dtb, A_log, Dvec, ybuf);

    // gate + rmsnorm
    gatenorm_kernel<<<NROWS, 256, 0, stream>>>(ybuf, zx, norm_w, gbuf);

    // out-proj GEMM -> d_out (f32)
    gemm_bt_kernel<false><<<dim3(KDIM / 128, NROWS / 128), 256, 0, stream>>>(
        gbuf, owbf, out, DINNER, KDIM);
}

// Round 2
// 789.308 us; speedup vs baseline: 1.9681x; 1.9681x over previous
//
#include <hip/hip_runtime.h>
#include <stdint.h>

typedef unsigned short ushort_t;
typedef __attribute__((ext_vector_type(4))) float f32x4;
typedef __attribute__((ext_vector_type(8))) short short8;
typedef __attribute__((ext_vector_type(4))) unsigned short us4;

#define L_SEQ   2048
#define NROWS   8192          // B*L = 4*2048
#define KDIM    1024
#define DINNER  2048
#define NHEADS  32
#define DSTATE  64
#define DCONVD  2176          // D_INNER + 2*D_STATE
#define NPROJ   4256
#define NPROJP  4352          // padded to 34*128
#define LDZX    4352
#define NCHUNK  32            // L / 64

__device__ __forceinline__ float bf2f(ushort_t u) {
    union { uint32_t i; float f; } v; v.i = ((uint32_t)u) << 16; return v.f;
}
__device__ __forceinline__ ushort_t f2bf(float f) {
    uint32_t x = __float_as_uint(f);
    x += 0x7FFFu + ((x >> 16) & 1u);
    return (ushort_t)(x >> 16);
}

// ---------------- cast kernels ----------------
__global__ __launch_bounds__(256) void cast_bf16_kernel(const float* __restrict__ in,
                                                        ushort_t* __restrict__ out, int n4) {
    int i = blockIdx.x * 256 + threadIdx.x;
    if (i >= n4) return;
    float4 v = ((const float4*)in)[i];
    ushort4 o;
    o.x = f2bf(v.x); o.y = f2bf(v.y); o.z = f2bf(v.z); o.w = f2bf(v.w);
    ((ushort4*)out)[i] = o;
}

__global__ __launch_bounds__(256) void cast_pad_w_kernel(const float* __restrict__ w,
                                                         ushort_t* __restrict__ out) {
    int i = blockIdx.x * 256 + threadIdx.x;   // group of 4 elems
    int idx = i * 4;
    int row = idx >> 10;
    ushort4 o;
    if (row < NPROJ) {
        float4 v = ((const float4*)w)[i];
        o.x = f2bf(v.x); o.y = f2bf(v.y); o.z = f2bf(v.z); o.w = f2bf(v.w);
    } else {
        o.x = 0; o.y = 0; o.z = 0; o.w = 0;
    }
    ((ushort4*)out)[i] = o;
}

// ---------------- MFMA GEMM:  C[M][N] = A[M][K] * B[N][K]^T ----------------
__device__ __forceinline__ void async16(const void* g, void* l) {
    __builtin_amdgcn_global_load_lds((const __attribute__((address_space(1))) void*)g,
                                     (__attribute__((address_space(3))) void*)l, 16, 0, 0);
}

template<bool OUT_BF16>
__global__ __launch_bounds__(256) void gemm_bt_kernel(const ushort_t* __restrict__ A,
                                                      const ushort_t* __restrict__ B,
                                                      void* __restrict__ Cp,
                                                      const int K, const int ldc) {
    __shared__ ushort_t As[4096];   // [128][32] bf16
    __shared__ ushort_t Bs[4096];
    const int tid  = threadIdx.x;
    const int wave = tid >> 6;
    const int lane = tid & 63;
    const int llo  = lane & 15;
    const int lhi  = lane >> 4;
    const int m0 = blockIdx.y * 128;
    const int n0 = blockIdx.x * 128;
    const int wr = wave >> 1, wc = wave & 1;

    f32x4 acc[4][4];
    const f32x4 zero = {0.f, 0.f, 0.f, 0.f};
#pragma unroll
    for (int i = 0; i < 4; ++i)
#pragma unroll
        for (int j = 0; j < 4; ++j) acc[i][j] = zero;

    const int srow = tid >> 2;
    const int skq  = tid & 3;
    const ushort_t* gA = A + (size_t)(m0 + srow) * K + skq * 8;
    const ushort_t* gB = B + (size_t)(n0 + srow) * K + skq * 8;
    ushort_t* lA0 = As + wave * 512;
    ushort_t* lA1 = As + 2048 + wave * 512;
    ushort_t* lB0 = Bs + wave * 512;
    ushort_t* lB1 = Bs + 2048 + wave * 512;
    const size_t rstep = (size_t)64 * K;

    const ushort_t* pa = As + (wr * 64 + llo) * 32 + lhi * 8;
    const ushort_t* pb = Bs + (wc * 64 + llo) * 32 + lhi * 8;

    for (int k0 = 0; k0 < K; k0 += 32) {
        __syncthreads();
        async16(gA + k0, lA0);
        async16(gA + rstep + k0, lA1);
        async16(gB + k0, lB0);
        async16(gB + rstep + k0, lB1);
        __syncthreads();
        short8 af[4], bfr[4];
#pragma unroll
        for (int i = 0; i < 4; ++i) af[i]  = *(const short8*)(pa + i * 512);
#pragma unroll
        for (int j = 0; j < 4; ++j) bfr[j] = *(const short8*)(pb + j * 512);
#pragma unroll
        for (int i = 0; i < 4; ++i)
#pragma unroll
            for (int j = 0; j < 4; ++j)
                acc[i][j] = __builtin_amdgcn_mfma_f32_16x16x32_bf16(af[i], bfr[j], acc[i][j], 0, 0, 0);
    }

#pragma unroll
    for (int i = 0; i < 4; ++i)
#pragma unroll
        for (int j = 0; j < 4; ++j) {
            const int col = n0 + wc * 64 + j * 16 + llo;
            const int rowb = m0 + wr * 64 + i * 16 + lhi * 4;
#pragma unroll
            for (int r = 0; r < 4; ++r) {
                if (OUT_BF16) {
                    ((ushort_t*)Cp)[(size_t)(rowb + r) * ldc + col] = f2bf(acc[i][j][r]);
                } else {
                    ((float*)Cp)[(size_t)(rowb + r) * ldc + col] = acc[i][j][r];
                }
            }
        }
}

// ---------------- conv (4-tap causal) + SiLU ----------------
__global__ __launch_bounds__(256) void conv_silu_kernel(const ushort_t* __restrict__ zx,
                                                        const float* __restrict__ conv_w,
                                                        const float* __restrict__ conv_b,
                                                        ushort_t* __restrict__ convout) {
    const int c = blockIdx.x * 256 + threadIdx.x;
    const int row = blockIdx.y;
    if (c >= DCONVD) return;
    const int l = row & (L_SEQ - 1);
    float acc = conv_b[c];
#pragma unroll
    for (int k = 0; k < 4; ++k) {
        int ll = l - 3 + k;
        if (ll >= 0)
            acc += bf2f(zx[(size_t)(row - 3 + k) * LDZX + DINNER + c]) * conv_w[c * 4 + k];
    }
    float s = acc / (1.f + expf(-acc));
    convout[(size_t)row * DCONVD + c] = f2bf(s);
}

// ---------------- dt = softplus(raw + bias) ----------------
__global__ __launch_bounds__(256) void dt_kernel(const ushort_t* __restrict__ zx,
                                                 const float* __restrict__ dt_bias,
                                                 float* __restrict__ dtb) {
    int idx = blockIdx.x * 256 + threadIdx.x;   // NROWS*32
    int row = idx >> 5;
    int h = idx & 31;
    float v = bf2f(zx[(size_t)row * LDZX + NPROJ - NHEADS + h]) + dt_bias[h];
    dtb[idx] = (v > 20.f) ? v : log1pf(expf(v));
}

// ---------------- Phase A: per-chunk intra output + chunk state G ----------------
// One WG per (chunk c, head h, batch b). Q = 64.
// S[i][j] = (C_i . B_j) * exp(P_i - P_j) * dt_j   (j<=i),  + D on diagonal
// Y_intra = S @ X      -> ybuf (bf16)
// G[p][n] = sum_j exp(P63-P_j) dt_j X[j][p] B[j][n]  -> Gbuf (bf16)
// expP[t] = exp(P_t)   -> global (f32), sEp[63] is the chunk decay E_c
__global__ __launch_bounds__(256) void chunk_intra_kernel(
    const ushort_t* __restrict__ cvb, const float* __restrict__ dtb,
    const float* __restrict__ A_log, const float* __restrict__ Dvec,
    ushort_t* __restrict__ ybuf, ushort_t* __restrict__ Gbuf,
    float* __restrict__ expPb)
{
    const int c = blockIdx.x, h = blockIdx.y, b = blockIdx.z;
    const int tid = threadIdx.x;

    __shared__ float CsT[4096];    // [n][t]  (reused as Bsr [j][n] for step5)
    __shared__ float BsT[4096];    // [n][t]
    __shared__ float Xs[4096];     // [t][p]
    __shared__ ushort_t Ssb[4096]; // [j][i] bf16, col-xor-swizzled
    __shared__ float sP[64], sdt[64], sW[64];

    const int t4 = tid >> 2, qq = tid & 3;
    const size_t rowg0 = (size_t)b * L_SEQ + c * 64;
    const ushort_t* rowp = cvb + (rowg0 + t4) * DCONVD;

    short8 rb0 = *(const short8*)(rowp + DINNER + qq * 16);
    short8 rb1 = *(const short8*)(rowp + DINNER + qq * 16 + 8);
    short8 rc0 = *(const short8*)(rowp + DINNER + DSTATE + qq * 16);
    short8 rc1 = *(const short8*)(rowp + DINNER + DSTATE + qq * 16 + 8);
    short8 rx0 = *(const short8*)(rowp + h * 64 + qq * 16);
    short8 rx1 = *(const short8*)(rowp + h * 64 + qq * 16 + 8);

#pragma unroll
    for (int k = 0; k < 8; ++k) {
        BsT[(qq * 16 + k) * 64 + t4]     = bf2f((ushort_t)rb0[k]);
        BsT[(qq * 16 + 8 + k) * 64 + t4] = bf2f((ushort_t)rb1[k]);
        CsT[(qq * 16 + k) * 64 + t4]     = bf2f((ushort_t)rc0[k]);
        CsT[(qq * 16 + 8 + k) * 64 + t4] = bf2f((ushort_t)rc1[k]);
    }
    {
        f32x4* xw = (f32x4*)&Xs[t4 * 64 + qq * 16];
        f32x4 v;
        v[0] = bf2f((ushort_t)rx0[0]); v[1] = bf2f((ushort_t)rx0[1]);
        v[2] = bf2f((ushort_t)rx0[2]); v[3] = bf2f((ushort_t)rx0[3]); xw[0] = v;
        v[0] = bf2f((ushort_t)rx0[4]); v[1] = bf2f((ushort_t)rx0[5]);
        v[2] = bf2f((ushort_t)rx0[6]); v[3] = bf2f((ushort_t)rx0[7]); xw[1] = v;
        v[0] = bf2f((ushort_t)rx1[0]); v[1] = bf2f((ushort_t)rx1[1]);
        v[2] = bf2f((ushort_t)rx1[2]); v[3] = bf2f((ushort_t)rx1[3]); xw[2] = v;
        v[0] = bf2f((ushort_t)rx1[4]); v[1] = bf2f((ushort_t)rx1[5]);
        v[2] = bf2f((ushort_t)rx1[6]); v[3] = bf2f((ushort_t)rx1[7]); xw[3] = v;
    }
    if (tid < 64) {
        float dt = dtb[(rowg0 + tid) * NHEADS + h];
        float A = -__expf(A_log[h]);
        float P = dt * A;
#pragma unroll
        for (int off = 1; off < 64; off <<= 1) {
            float o = __shfl_up(P, off);
            if (tid >= off) P += o;
        }
        sP[tid] = P;
        sdt[tid] = dt;
        float P63 = __shfl(P, 63);
        sW[tid] = __expf(P63 - P) * dt;
        expPb[(size_t)(b * NHEADS + h) * L_SEQ + c * 64 + tid] = __expf(P);
    }
    __syncthreads();

    const int ti = tid >> 4, tj = tid & 15;
    const float Dh = Dvec[h];

    // ---- step 3: S = C . B^T, mask/scale, store bf16 ----
    float acc[4][4];
#pragma unroll
    for (int ii = 0; ii < 4; ++ii)
#pragma unroll
        for (int jj = 0; jj < 4; ++jj) acc[ii][jj] = 0.f;
#pragma unroll 4
    for (int n = 0; n < 64; ++n) {
        f32x4 cv = *(const f32x4*)&CsT[n * 64 + ti * 4];
        f32x4 bv = *(const f32x4*)&BsT[n * 64 + tj * 4];
#pragma unroll
        for (int ii = 0; ii < 4; ++ii)
#pragma unroll
            for (int jj = 0; jj < 4; ++jj)
                acc[ii][jj] += cv[ii] * bv[jj];
    }
#pragma unroll
    for (int ii = 0; ii < 4; ++ii) {
        const int i = ti * 4 + ii;
        const float Pi = sP[i];
#pragma unroll
        for (int jj = 0; jj < 4; ++jj) {
            const int j = tj * 4 + jj;
            float s = 0.f;
            if (j <= i) s = acc[ii][jj] * __expf(Pi - sP[j]) * sdt[j];
            if (j == i) s += Dh;
            Ssb[j * 64 + (i ^ ((j & 7) << 3))] = f2bf(s);
        }
    }
    __syncthreads();

    // write B row-major into CsT region (from registers; CsT reads are done)
    {
        float* Bsr = CsT;
        f32x4* bw = (f32x4*)&Bsr[t4 * 64 + qq * 16];
        f32x4 v;
        v[0] = bf2f((ushort_t)rb0[0]); v[1] = bf2f((ushort_t)rb0[1]);
        v[2] = bf2f((ushort_t)rb0[2]); v[3] = bf2f((ushort_t)rb0[3]); bw[0] = v;
        v[0] = bf2f((ushort_t)rb0[4]); v[1] = bf2f((ushort_t)rb0[5]);
        v[2] = bf2f((ushort_t)rb0[6]); v[3] = bf2f((ushort_t)rb0[7]); bw[1] = v;
        v[0] = bf2f((ushort_t)rb1[0]); v[1] = bf2f((ushort_t)rb1[1]);
        v[2] = bf2f((ushort_t)rb1[2]); v[3] = bf2f((ushort_t)rb1[3]); bw[2] = v;
        v[0] = bf2f((ushort_t)rb1[4]); v[1] = bf2f((ushort_t)rb1[5]);
        v[2] = bf2f((ushort_t)rb1[6]); v[3] = bf2f((ushort_t)rb1[7]); bw[3] = v;
    }

    // ---- step 4: Y_intra = S @ X  (D already on S diagonal) ----
    float acc2[4][4];
#pragma unroll
    for (int ii = 0; ii < 4; ++ii)
#pragma unroll
        for (int jj = 0; jj < 4; ++jj) acc2[ii][jj] = 0.f;
#pragma unroll 4
    for (int j = 0; j < 64; ++j) {
        us4 sv = *(const us4*)&Ssb[j * 64 + ((ti * 4) ^ ((j & 7) << 3))];
        f32x4 xv = *(const f32x4*)&Xs[j * 64 + tj * 4];
#pragma unroll
        for (int ii = 0; ii < 4; ++ii) {
            float sf = bf2f(sv[ii]);
#pragma unroll
            for (int jj = 0; jj < 4; ++jj)
                acc2[ii][jj] += sf * xv[jj];
        }
    }
#pragma unroll
    for (int ii = 0; ii < 4; ++ii) {
        us4 o;
#pragma unroll
        for (int jj = 0; jj < 4; ++jj) o[jj] = f2bf(acc2[ii][jj]);
        *(us4*)&ybuf[(rowg0 + ti * 4 + ii) * DINNER + h * 64 + tj * 4] = o;
    }
    __syncthreads();

    // ---- step 5: G[p][n] = sum_j w_j X[j][p] B[j][n] ----
    float acc3[4][4];
#pragma unroll
    for (int ii = 0; ii < 4; ++ii)
#pragma unroll
        for (int jj = 0; jj < 4; ++jj) acc3[ii][jj] = 0.f;
#pragma unroll 4
    for (int j = 0; j < 64; ++j) {
        const float w = sW[j];
        f32x4 xv = *(const f32x4*)&Xs[j * 64 + ti * 4];
        f32x4 bv = *(const f32x4*)&CsT[j * 64 + tj * 4];  // Bsr
#pragma unroll
        for (int ii = 0; ii < 4; ++ii) {
            float wx = w * xv[ii];
#pragma unroll
            for (int jj = 0; jj < 4; ++jj)
                acc3[ii][jj] += wx * bv[jj];
        }
    }
    const size_t gbase = ((size_t)((b * NHEADS + h) * NCHUNK + c)) << 12;
#pragma unroll
    for (int ii = 0; ii < 4; ++ii) {
        us4 o;
#pragma unroll
        for (int jj = 0; jj < 4; ++jj) o[jj] = f2bf(acc3[ii][jj]);
        *(us4*)&Gbuf[gbase + (ti * 4 + ii) * 64 + tj * 4] = o;
    }
}

// ---------------- Phase B: carry chunk states, add inter-chunk y ----------------
// One WG (128 threads) per (p-half po, head h, batch b). 32 serial chunk steps.
__global__ __launch_bounds__(128) void chunk_carry_kernel(
    const ushort_t* __restrict__ cvb, const float* __restrict__ expPb,
    const ushort_t* __restrict__ Gbuf, ushort_t* __restrict__ ybuf)
{
    const int po = blockIdx.x, h = blockIdx.y, b = blockIdx.z;
    const int tid = threadIdx.x;
    const int pl = tid >> 2, q = tid & 3;
    const int p = po * 32 + pl;
    const int bh = b * NHEADS + h;

    __shared__ float sCc[4096];   // [t][n]
    __shared__ float sY[2048];    // [t][pl]
    __shared__ float sEp[64];

    float hreg[16];
#pragma unroll
    for (int k = 0; k < 16; ++k) hreg[k] = 0.f;

    const int lt = tid >> 1, lh = tid & 1;

    for (int cc = 0; cc < NCHUNK; ++cc) {
        __syncthreads();
        {
            const ushort_t* rp = cvb + ((size_t)b * L_SEQ + cc * 64 + lt) * DCONVD
                                 + DINNER + DSTATE + lh * 32;
            short8 v0 = *(const short8*)(rp);
            short8 v1 = *(const short8*)(rp + 8);
            short8 v2 = *(const short8*)(rp + 16);
            short8 v3 = *(const short8*)(rp + 24);
            float* dst = &sCc[lt * 64 + lh * 32];
#pragma unroll
            for (int k = 0; k < 8; ++k) {
                dst[k]      = bf2f((ushort_t)v0[k]);
                dst[8 + k]  = bf2f((ushort_t)v1[k]);
                dst[16 + k] = bf2f((ushort_t)v2[k]);
                dst[24 + k] = bf2f((ushort_t)v3[k]);
            }
            if (tid < 64) sEp[tid] = expPb[(size_t)bh * L_SEQ + cc * 64 + tid];
        }
        __syncthreads();

        if (cc > 0) {
#pragma unroll 2
            for (int t = 0; t < 64; ++t) {
                const f32x4* cp = (const f32x4*)&sCc[t * 64 + q * 16];
                float a = 0.f;
#pragma unroll
                for (int m = 0; m < 4; ++m) {
                    f32x4 cv = cp[m];
                    a += cv[0] * hreg[4 * m] + cv[1] * hreg[4 * m + 1]
                       + cv[2] * hreg[4 * m + 2] + cv[3] * hreg[4 * m + 3];
                }
                a += __shfl_xor(a, 1);
                a += __shfl_xor(a, 2);
                if (q == 0) sY[t * 32 + pl] = a * sEp[t];
            }
            __syncthreads();
            ushort_t* yp = ybuf + ((size_t)b * L_SEQ + cc * 64 + lt) * DINNER
                           + h * 64 + po * 32 + lh * 16;
            short8 y0 = *(short8*)yp;
            short8 y1 = *(short8*)(yp + 8);
            const float* sp = &sY[lt * 32 + lh * 16];
            short8 o0, o1;
#pragma unroll
            for (int k = 0; k < 8; ++k) {
                o0[k] = (short)f2bf(bf2f((ushort_t)y0[k]) + sp[k]);
                o1[k] = (short)f2bf(bf2f((ushort_t)y1[k]) + sp[8 + k]);
            }
            *(short8*)yp = o0;
            *(short8*)(yp + 8) = o1;
        }
        {
            const float Ec = sEp[63];
            const ushort_t* gp = Gbuf + (((size_t)bh * NCHUNK + cc) << 12) + p * 64 + q * 16;
            short8 g0 = *(const short8*)gp;
            short8 g1 = *(const short8*)(gp + 8);
#pragma unroll
            for (int k = 0; k < 8; ++k) {
                hreg[k]     = hreg[k] * Ec + bf2f((ushort_t)g0[k]);
                hreg[8 + k] = hreg[8 + k] * Ec + bf2f((ushort_t)g1[k]);
            }
        }
    }
}

// ---------------- gate (y * silu(z)) + RMSNorm -> bf16 ----------------
__global__ __launch_bounds__(256) void gatenorm_kernel(const ushort_t* __restrict__ ybuf,
                                                       const ushort_t* __restrict__ zx,
                                                       const float* __restrict__ norm_w,
                                                       ushort_t* __restrict__ gbuf) {
    const int row = blockIdx.x;
    const int tid = threadIdx.x;
    short8 yv = *(const short8*)(ybuf + (size_t)row * DINNER + tid * 8);
    short8 zv = *(const short8*)(zx + (size_t)row * LDZX + tid * 8);
    float g[8];
    float ss = 0.f;
#pragma unroll
    for (int i = 0; i < 8; ++i) {
        float y = bf2f((ushort_t)yv[i]);
        float z = bf2f((ushort_t)zv[i]);
        float sz = z / (1.f + expf(-z));
        float gg = y * sz;
        g[i] = gg;
        ss += gg * gg;
    }
#pragma unroll
    for (int o = 32; o > 0; o >>= 1) ss += __shfl_xor(ss, o);
    __shared__ float wsum[4];
    if ((tid & 63) == 0) wsum[tid >> 6] = ss;
    __syncthreads();
    float tot = wsum[0] + wsum[1] + wsum[2] + wsum[3];
    float scale = rsqrtf(tot * (1.0f / (float)DINNER) + 1e-5f);
    short8 o8;
#pragma unroll
    for (int i = 0; i < 8; ++i)
        o8[i] = (short)f2bf(g[i] * scale * norm_w[tid * 8 + i]);
    *(short8*)(gbuf + (size_t)row * DINNER + tid * 8) = o8;
}

// ---------------- launch ----------------
extern "C" void kernel_launch(void* const* d_in, const int* in_sizes, int n_in,
                              void* d_out, int out_size, void* d_ws, size_t ws_size,
                              hipStream_t stream) {
    const float* x          = (const float*)d_in[0];
    const float* in_proj_w  = (const float*)d_in[1];
    const float* conv_w     = (const float*)d_in[2];
    const float* conv_b     = (const float*)d_in[3];
    const float* dt_bias    = (const float*)d_in[4];
    const float* A_log      = (const float*)d_in[5];
    const float* Dvec       = (const float*)d_in[6];
    const float* norm_w     = (const float*)d_in[7];
    const float* out_proj_w = (const float*)d_in[8];
    float* out = (float*)d_out;

    char* ws = (char*)d_ws;
    size_t off = 0;
    ushort_t* owbf  = (ushort_t*)(ws + off); off += (size_t)KDIM * DINNER * 2;     // 4.2 MB
    ushort_t* zx    = (ushort_t*)(ws + off); off += (size_t)NROWS * LDZX * 2;      // 71.3 MB
    ushort_t* cvb   = (ushort_t*)(ws + off); off += (size_t)NROWS * DCONVD * 2;    // 35.7 MB
    float*    dtb   = (float*)(ws + off);    off += (size_t)NROWS * NHEADS * 4;    // 1.05 MB
    float*    expPb = (float*)(ws + off);    off += (size_t)128 * L_SEQ * 4;       // 1.05 MB
    ushort_t* ybuf  = (ushort_t*)(ws + off); off += (size_t)NROWS * DINNER * 2;    // 33.6 MB
    // tail region (33.6 MB), time-multiplexed:
    //   stage 1: xbf (16.8) + wbf (8.9)  — dead after GEMM1
    //   stage 2: Gbuf (33.6)             — dead after chunk_carry
    //   stage 3: gbuf (33.6)             — dead after GEMM2
    char* tail = ws + off;
    ushort_t* xbf  = (ushort_t*)tail;
    ushort_t* wbf  = (ushort_t*)(tail + (size_t)NROWS * KDIM * 2);
    ushort_t* Gbuf = (ushort_t*)tail;
    ushort_t* gbuf = (ushort_t*)tail;

    // casts
    cast_bf16_kernel<<<8192, 256, 0, stream>>>(x, xbf, NROWS * KDIM / 4);
    cast_pad_w_kernel<<<4352, 256, 0, stream>>>(in_proj_w, wbf);
    cast_bf16_kernel<<<2048, 256, 0, stream>>>(out_proj_w, owbf, KDIM * DINNER / 4);

    // in-proj GEMM: zx[8192][4352] (bf16)
    gemm_bt_kernel<true><<<dim3(NPROJP / 128, NROWS / 128), 256, 0, stream>>>(
        xbf, wbf, zx, KDIM, LDZX);

    // conv + silu
    conv_silu_kernel<<<dim3((DCONVD + 255) / 256, NROWS), 256, 0, stream>>>(zx, conv_w, conv_b, cvb);

    // dt
    dt_kernel<<<NROWS * NHEADS / 256, 256, 0, stream>>>(zx, dt_bias, dtb);

    // chunked scan: phase A (parallel) + phase B (32 serial steps)
    chunk_intra_kernel<<<dim3(NCHUNK, NHEADS, 4), 256, 0, stream>>>(
        cvb, dtb, A_log, Dvec, ybuf, Gbuf, expPb);
    chunk_carry_kernel<<<dim3(2, NHEADS, 4), 128, 0, stream>>>(
        cvb, expPb, Gbuf, ybuf);

    // gate + rmsnorm
    gatenorm_kernel<<<NROWS, 256, 0, stream>>>(ybuf, zx, norm_w, gbuf);

    // out-proj GEMM -> d_out (f32)
    gemm_bt_kernel<false><<<dim3(KDIM / 128, NROWS / 128), 256, 0, stream>>>(
        gbuf, owbf, out, DINNER, KDIM);
}

// Round 3
// 440.876 us; speedup vs baseline: 3.5235x; 1.7903x over previous
//
#include <hip/hip_runtime.h>
#include <stdint.h>

typedef unsigned short ushort_t;
typedef __attribute__((ext_vector_type(4))) float f32x4;
typedef __attribute__((ext_vector_type(8))) short short8;
typedef __attribute__((ext_vector_type(4))) unsigned short us4;

#define L_SEQ   2048
#define NROWS   8192          // B*L = 4*2048
#define KDIM    1024
#define DINNER  2048
#define NHEADS  32
#define DSTATE  64
#define DCONVD  2176          // D_INNER + 2*D_STATE
#define NPROJ   4256
#define NPROJP  4352          // padded to 34*128
#define LDZX    4352
#define NCHUNK  32            // L / 64

__device__ __forceinline__ float bf2f(ushort_t u) {
    union { uint32_t i; float f; } v; v.i = ((uint32_t)u) << 16; return v.f;
}
__device__ __forceinline__ ushort_t f2bf(float f) {
    uint32_t x = __float_as_uint(f);
    x += 0x7FFFu + ((x >> 16) & 1u);
    return (ushort_t)(x >> 16);
}

// ---------------- cast kernels ----------------
__global__ __launch_bounds__(256) void cast_bf16_kernel(const float* __restrict__ in,
                                                        ushort_t* __restrict__ out, int n4) {
    int i = blockIdx.x * 256 + threadIdx.x;
    if (i >= n4) return;
    float4 v = ((const float4*)in)[i];
    ushort4 o;
    o.x = f2bf(v.x); o.y = f2bf(v.y); o.z = f2bf(v.z); o.w = f2bf(v.w);
    ((ushort4*)out)[i] = o;
}

__global__ __launch_bounds__(256) void cast_pad_w_kernel(const float* __restrict__ w,
                                                         ushort_t* __restrict__ out) {
    int i = blockIdx.x * 256 + threadIdx.x;   // group of 4 elems
    int idx = i * 4;
    int row = idx >> 10;
    ushort4 o;
    if (row < NPROJ) {
        float4 v = ((const float4*)w)[i];
        o.x = f2bf(v.x); o.y = f2bf(v.y); o.z = f2bf(v.z); o.w = f2bf(v.w);
    } else {
        o.x = 0; o.y = 0; o.z = 0; o.w = 0;
    }
    ((ushort4*)out)[i] = o;
}

// ---------------- MFMA GEMM:  C[M][N] = A[M][K] * B[N][K]^T ----------------
__device__ __forceinline__ void async16(const void* g, void* l) {
    __builtin_amdgcn_global_load_lds((const __attribute__((address_space(1))) void*)g,
                                     (__attribute__((address_space(3))) void*)l, 16, 0, 0);
}

template<bool OUT_BF16>
__global__ __launch_bounds__(256) void gemm_bt_kernel(const ushort_t* __restrict__ A,
                                                      const ushort_t* __restrict__ B,
                                                      void* __restrict__ Cp,
                                                      const int K, const int ldc) {
    __shared__ ushort_t As[4096];   // [128][32] bf16
    __shared__ ushort_t Bs[4096];
    const int tid  = threadIdx.x;
    const int wave = tid >> 6;
    const int lane = tid & 63;
    const int llo  = lane & 15;
    const int lhi  = lane >> 4;
    const int m0 = blockIdx.y * 128;
    const int n0 = blockIdx.x * 128;
    const int wr = wave >> 1, wc = wave & 1;

    f32x4 acc[4][4];
    const f32x4 zero = {0.f, 0.f, 0.f, 0.f};
#pragma unroll
    for (int i = 0; i < 4; ++i)
#pragma unroll
        for (int j = 0; j < 4; ++j) acc[i][j] = zero;

    const int srow = tid >> 2;
    const int skq  = tid & 3;
    const ushort_t* gA = A + (size_t)(m0 + srow) * K + skq * 8;
    const ushort_t* gB = B + (size_t)(n0 + srow) * K + skq * 8;
    ushort_t* lA0 = As + wave * 512;
    ushort_t* lA1 = As + 2048 + wave * 512;
    ushort_t* lB0 = Bs + wave * 512;
    ushort_t* lB1 = Bs + 2048 + wave * 512;
    const size_t rstep = (size_t)64 * K;

    const ushort_t* pa = As + (wr * 64 + llo) * 32 + lhi * 8;
    const ushort_t* pb = Bs + (wc * 64 + llo) * 32 + lhi * 8;

    for (int k0 = 0; k0 < K; k0 += 32) {
        __syncthreads();
        async16(gA + k0, lA0);
        async16(gA + rstep + k0, lA1);
        async16(gB + k0, lB0);
        async16(gB + rstep + k0, lB1);
        __syncthreads();
        short8 af[4], bfr[4];
#pragma unroll
        for (int i = 0; i < 4; ++i) af[i]  = *(const short8*)(pa + i * 512);
#pragma unroll
        for (int j = 0; j < 4; ++j) bfr[j] = *(const short8*)(pb + j * 512);
#pragma unroll
        for (int i = 0; i < 4; ++i)
#pragma unroll
            for (int j = 0; j < 4; ++j)
                acc[i][j] = __builtin_amdgcn_mfma_f32_16x16x32_bf16(af[i], bfr[j], acc[i][j], 0, 0, 0);
    }

#pragma unroll
    for (int i = 0; i < 4; ++i)
#pragma unroll
        for (int j = 0; j < 4; ++j) {
            const int col = n0 + wc * 64 + j * 16 + llo;
            const int rowb = m0 + wr * 64 + i * 16 + lhi * 4;
#pragma unroll
            for (int r = 0; r < 4; ++r) {
                if (OUT_BF16) {
                    ((ushort_t*)Cp)[(size_t)(rowb + r) * ldc + col] = f2bf(acc[i][j][r]);
                } else {
                    ((float*)Cp)[(size_t)(rowb + r) * ldc + col] = acc[i][j][r];
                }
            }
        }
}

// ---------------- conv (4-tap causal) + SiLU ----------------
__global__ __launch_bounds__(256) void conv_silu_kernel(const ushort_t* __restrict__ zx,
                                                        const float* __restrict__ conv_w,
                                                        const float* __restrict__ conv_b,
                                                        ushort_t* __restrict__ convout) {
    const int c = blockIdx.x * 256 + threadIdx.x;
    const int row = blockIdx.y;
    if (c >= DCONVD) return;
    const int l = row & (L_SEQ - 1);
    float acc = conv_b[c];
#pragma unroll
    for (int k = 0; k < 4; ++k) {
        int ll = l - 3 + k;
        if (ll >= 0)
            acc += bf2f(zx[(size_t)(row - 3 + k) * LDZX + DINNER + c]) * conv_w[c * 4 + k];
    }
    float s = acc / (1.f + expf(-acc));
    convout[(size_t)row * DCONVD + c] = f2bf(s);
}

// ---------------- dt = softplus(raw + bias) ----------------
__global__ __launch_bounds__(256) void dt_kernel(const ushort_t* __restrict__ zx,
                                                 const float* __restrict__ dt_bias,
                                                 float* __restrict__ dtb) {
    int idx = blockIdx.x * 256 + threadIdx.x;   // NROWS*32
    int row = idx >> 5;
    int h = idx & 31;
    float v = bf2f(zx[(size_t)row * LDZX + NPROJ - NHEADS + h]) + dt_bias[h];
    dtb[idx] = (v > 20.f) ? v : log1pf(expf(v));
}

// ---------------- Phase A: per-chunk intra output + chunk state G ----------------
// One WG per (chunk c, head h, batch b). Q = 64.
// S[i][j] = (C_i . B_j) * exp(P_i - P_j) * dt_j   (j<=i),  + D on diagonal
// Y_intra = S @ X      -> ybuf (bf16)
// G[n][p] = sum_j exp(P63-P_j) dt_j X[j][p] B[j][n]  -> Gbuf (bf16, [n][p] layout)
// expP[t] = exp(P_t)   -> global (f32)
__global__ __launch_bounds__(256) void chunk_intra_kernel(
    const ushort_t* __restrict__ cvb, const float* __restrict__ dtb,
    const float* __restrict__ A_log, const float* __restrict__ Dvec,
    ushort_t* __restrict__ ybuf, ushort_t* __restrict__ Gbuf,
    float* __restrict__ expPb)
{
    const int c = blockIdx.x, h = blockIdx.y, b = blockIdx.z;
    const int tid = threadIdx.x;

    __shared__ float CsT[4096];    // [n][t]  (reused as Bsr [j][n] for step5)
    __shared__ float BsT[4096];    // [n][t]
    __shared__ float Xs[4096];     // [t][p]
    __shared__ ushort_t Ssb[4096]; // [j][i] bf16, col-xor-swizzled
    __shared__ float sP[64], sdt[64], sW[64];

    const int t4 = tid >> 2, qq = tid & 3;
    const size_t rowg0 = (size_t)b * L_SEQ + c * 64;
    const ushort_t* rowp = cvb + (rowg0 + t4) * DCONVD;

    short8 rb0 = *(const short8*)(rowp + DINNER + qq * 16);
    short8 rb1 = *(const short8*)(rowp + DINNER + qq * 16 + 8);
    short8 rc0 = *(const short8*)(rowp + DINNER + DSTATE + qq * 16);
    short8 rc1 = *(const short8*)(rowp + DINNER + DSTATE + qq * 16 + 8);
    short8 rx0 = *(const short8*)(rowp + h * 64 + qq * 16);
    short8 rx1 = *(const short8*)(rowp + h * 64 + qq * 16 + 8);

#pragma unroll
    for (int k = 0; k < 8; ++k) {
        BsT[(qq * 16 + k) * 64 + t4]     = bf2f((ushort_t)rb0[k]);
        BsT[(qq * 16 + 8 + k) * 64 + t4] = bf2f((ushort_t)rb1[k]);
        CsT[(qq * 16 + k) * 64 + t4]     = bf2f((ushort_t)rc0[k]);
        CsT[(qq * 16 + 8 + k) * 64 + t4] = bf2f((ushort_t)rc1[k]);
    }
    {
        f32x4* xw = (f32x4*)&Xs[t4 * 64 + qq * 16];
        f32x4 v;
        v[0] = bf2f((ushort_t)rx0[0]); v[1] = bf2f((ushort_t)rx0[1]);
        v[2] = bf2f((ushort_t)rx0[2]); v[3] = bf2f((ushort_t)rx0[3]); xw[0] = v;
        v[0] = bf2f((ushort_t)rx0[4]); v[1] = bf2f((ushort_t)rx0[5]);
        v[2] = bf2f((ushort_t)rx0[6]); v[3] = bf2f((ushort_t)rx0[7]); xw[1] = v;
        v[0] = bf2f((ushort_t)rx1[0]); v[1] = bf2f((ushort_t)rx1[1]);
        v[2] = bf2f((ushort_t)rx1[2]); v[3] = bf2f((ushort_t)rx1[3]); xw[2] = v;
        v[0] = bf2f((ushort_t)rx1[4]); v[1] = bf2f((ushort_t)rx1[5]);
        v[2] = bf2f((ushort_t)rx1[6]); v[3] = bf2f((ushort_t)rx1[7]); xw[3] = v;
    }
    if (tid < 64) {
        float dt = dtb[(rowg0 + tid) * NHEADS + h];
        float A = -__expf(A_log[h]);
        float P = dt * A;
#pragma unroll
        for (int off = 1; off < 64; off <<= 1) {
            float o = __shfl_up(P, off);
            if (tid >= off) P += o;
        }
        sP[tid] = P;
        sdt[tid] = dt;
        float P63 = __shfl(P, 63);
        sW[tid] = __expf(P63 - P) * dt;
        expPb[(size_t)(b * NHEADS + h) * L_SEQ + c * 64 + tid] = __expf(P);
    }
    __syncthreads();

    const int ti = tid >> 4, tj = tid & 15;
    const float Dh = Dvec[h];

    // ---- step 3: S = C . B^T, mask/scale, store bf16 ----
    float acc[4][4];
#pragma unroll
    for (int ii = 0; ii < 4; ++ii)
#pragma unroll
        for (int jj = 0; jj < 4; ++jj) acc[ii][jj] = 0.f;
#pragma unroll 4
    for (int n = 0; n < 64; ++n) {
        f32x4 cv = *(const f32x4*)&CsT[n * 64 + ti * 4];
        f32x4 bv = *(const f32x4*)&BsT[n * 64 + tj * 4];
#pragma unroll
        for (int ii = 0; ii < 4; ++ii)
#pragma unroll
            for (int jj = 0; jj < 4; ++jj)
                acc[ii][jj] += cv[ii] * bv[jj];
    }
#pragma unroll
    for (int ii = 0; ii < 4; ++ii) {
        const int i = ti * 4 + ii;
        const float Pi = sP[i];
#pragma unroll
        for (int jj = 0; jj < 4; ++jj) {
            const int j = tj * 4 + jj;
            float s = 0.f;
            if (j <= i) s = acc[ii][jj] * __expf(Pi - sP[j]) * sdt[j];
            if (j == i) s += Dh;
            Ssb[j * 64 + (i ^ ((j & 7) << 3))] = f2bf(s);
        }
    }
    __syncthreads();

    // write B row-major into CsT region (from registers; CsT reads are done)
    {
        float* Bsr = CsT;
        f32x4* bw = (f32x4*)&Bsr[t4 * 64 + qq * 16];
        f32x4 v;
        v[0] = bf2f((ushort_t)rb0[0]); v[1] = bf2f((ushort_t)rb0[1]);
        v[2] = bf2f((ushort_t)rb0[2]); v[3] = bf2f((ushort_t)rb0[3]); bw[0] = v;
        v[0] = bf2f((ushort_t)rb0[4]); v[1] = bf2f((ushort_t)rb0[5]);
        v[2] = bf2f((ushort_t)rb0[6]); v[3] = bf2f((ushort_t)rb0[7]); bw[1] = v;
        v[0] = bf2f((ushort_t)rb1[0]); v[1] = bf2f((ushort_t)rb1[1]);
        v[2] = bf2f((ushort_t)rb1[2]); v[3] = bf2f((ushort_t)rb1[3]); bw[2] = v;
        v[0] = bf2f((ushort_t)rb1[4]); v[1] = bf2f((ushort_t)rb1[5]);
        v[2] = bf2f((ushort_t)rb1[6]); v[3] = bf2f((ushort_t)rb1[7]); bw[3] = v;
    }

    // ---- step 4: Y_intra = S @ X  (D already on S diagonal) ----
    float acc2[4][4];
#pragma unroll
    for (int ii = 0; ii < 4; ++ii)
#pragma unroll
        for (int jj = 0; jj < 4; ++jj) acc2[ii][jj] = 0.f;
#pragma unroll 4
    for (int j = 0; j < 64; ++j) {
        us4 sv = *(const us4*)&Ssb[j * 64 + ((ti * 4) ^ ((j & 7) << 3))];
        f32x4 xv = *(const f32x4*)&Xs[j * 64 + tj * 4];
#pragma unroll
        for (int ii = 0; ii < 4; ++ii) {
            float sf = bf2f(sv[ii]);
#pragma unroll
            for (int jj = 0; jj < 4; ++jj)
                acc2[ii][jj] += sf * xv[jj];
        }
    }
#pragma unroll
    for (int ii = 0; ii < 4; ++ii) {
        us4 o;
#pragma unroll
        for (int jj = 0; jj < 4; ++jj) o[jj] = f2bf(acc2[ii][jj]);
        *(us4*)&ybuf[(rowg0 + ti * 4 + ii) * DINNER + h * 64 + tj * 4] = o;
    }
    __syncthreads();

    // ---- step 5: G[n][p] = sum_j w_j X[j][p] B[j][n]  ([n][p] layout) ----
    float acc3[4][4];   // [ii -> p][jj -> n]
#pragma unroll
    for (int ii = 0; ii < 4; ++ii)
#pragma unroll
        for (int jj = 0; jj < 4; ++jj) acc3[ii][jj] = 0.f;
#pragma unroll 4
    for (int j = 0; j < 64; ++j) {
        const float w = sW[j];
        f32x4 xv = *(const f32x4*)&Xs[j * 64 + ti * 4];
        f32x4 bv = *(const f32x4*)&CsT[j * 64 + tj * 4];  // Bsr
#pragma unroll
        for (int ii = 0; ii < 4; ++ii) {
            float wx = w * xv[ii];
#pragma unroll
            for (int jj = 0; jj < 4; ++jj)
                acc3[ii][jj] += wx * bv[jj];
        }
    }
    const size_t gbase = ((size_t)((b * NHEADS + h) * NCHUNK + c)) << 12;
#pragma unroll
    for (int jj = 0; jj < 4; ++jj) {
        us4 o;
#pragma unroll
        for (int ii = 0; ii < 4; ++ii) o[ii] = f2bf(acc3[ii][jj]);
        *(us4*)&Gbuf[gbase + (size_t)(tj * 4 + jj) * 64 + ti * 4] = o;  // [n][p]
    }
}

// ---------------- Phase B1: elementwise chunk-state scan (in-place G -> hstates) ----------------
// GH[(bh*32+c)*4096 + e]: on entry G (chunk increment), on exit state ENTERING chunk c.
// Serial chain is 32 register FMAs per element; all loads independent (prefetched).
__global__ __launch_bounds__(256) void state_scan_kernel(
    ushort_t* __restrict__ GH, const float* __restrict__ expPb)
{
    const int half = blockIdx.x, h = blockIdx.y, b = blockIdx.z;
    const int bh = b * NHEADS + h;
    const int e0 = half * 2048 + threadIdx.x * 8;
    ushort_t* base = GH + ((size_t)bh << 17);
    const float* ep = expPb + (size_t)bh * L_SEQ;

    float hr[8];
#pragma unroll
    for (int k = 0; k < 8; ++k) hr[k] = 0.f;

    short8 g = *(const short8*)(base + e0);
    float Ec = ep[63];
    for (int c = 0; c < NCHUNK; ++c) {
        short8 gn = g; float En = 0.f;
        if (c + 1 < NCHUNK) {
            gn = *(const short8*)(base + ((size_t)(c + 1) << 12) + e0);
            En = ep[(c + 1) * 64 + 63];
        }
        short8 o;
#pragma unroll
        for (int k = 0; k < 8; ++k) o[k] = (short)f2bf(hr[k]);
        *(short8*)(base + ((size_t)c << 12) + e0) = o;
#pragma unroll
        for (int k = 0; k < 8; ++k) hr[k] = hr[k] * Ec + bf2f((ushort_t)g[k]);
        g = gn; Ec = En;
    }
}

// ---------------- Phase B2: y_inter[t][p] = expP[t] * sum_n C[t][n] * h_c[n][p] ----------------
// Fully parallel: one WG per (chunk c>=1, head h, batch b). RMW into ybuf.
__global__ __launch_bounds__(256) void y_inter_kernel(
    const ushort_t* __restrict__ cvb, const float* __restrict__ expPb,
    const ushort_t* __restrict__ hst, ushort_t* __restrict__ ybuf)
{
    const int c = blockIdx.x + 1, h = blockIdx.y, b = blockIdx.z;
    const int tid = threadIdx.x;
    const int bh = b * NHEADS + h;

    __shared__ float CsT[4096];   // [n][t]
    __shared__ float Hs[4096];    // [n][p]
    __shared__ float sEp[64];

    const int t4 = tid >> 2, qq = tid & 3;
    const size_t rowg0 = (size_t)b * L_SEQ + c * 64;
    {   // stage C^T
        const ushort_t* rp = cvb + (rowg0 + t4) * DCONVD + DINNER + DSTATE + qq * 16;
        short8 v0 = *(const short8*)rp;
        short8 v1 = *(const short8*)(rp + 8);
#pragma unroll
        for (int k = 0; k < 8; ++k) {
            CsT[(qq * 16 + k) * 64 + t4]     = bf2f((ushort_t)v0[k]);
            CsT[(qq * 16 + 8 + k) * 64 + t4] = bf2f((ushort_t)v1[k]);
        }
    }
    {   // stage H ([n][p] linear)
        const ushort_t* hp = hst + (((size_t)(bh * NCHUNK + c)) << 12) + tid * 16;
        short8 v0 = *(const short8*)hp;
        short8 v1 = *(const short8*)(hp + 8);
        f32x4* d = (f32x4*)&Hs[tid * 16];
        f32x4 v;
        v[0] = bf2f((ushort_t)v0[0]); v[1] = bf2f((ushort_t)v0[1]);
        v[2] = bf2f((ushort_t)v0[2]); v[3] = bf2f((ushort_t)v0[3]); d[0] = v;
        v[0] = bf2f((ushort_t)v0[4]); v[1] = bf2f((ushort_t)v0[5]);
        v[2] = bf2f((ushort_t)v0[6]); v[3] = bf2f((ushort_t)v0[7]); d[1] = v;
        v[0] = bf2f((ushort_t)v1[0]); v[1] = bf2f((ushort_t)v1[1]);
        v[2] = bf2f((ushort_t)v1[2]); v[3] = bf2f((ushort_t)v1[3]); d[2] = v;
        v[0] = bf2f((ushort_t)v1[4]); v[1] = bf2f((ushort_t)v1[5]);
        v[2] = bf2f((ushort_t)v1[6]); v[3] = bf2f((ushort_t)v1[7]); d[3] = v;
    }
    if (tid < 64) sEp[tid] = expPb[(size_t)bh * L_SEQ + c * 64 + tid];
    __syncthreads();

    const int ti = tid >> 4, tj = tid & 15;
    float acc[4][4];
#pragma unroll
    for (int ii = 0; ii < 4; ++ii)
#pragma unroll
        for (int jj = 0; jj < 4; ++jj) acc[ii][jj] = 0.f;
#pragma unroll 4
    for (int n = 0; n < 64; ++n) {
        f32x4 cv = *(const f32x4*)&CsT[n * 64 + ti * 4];
        f32x4 hv = *(const f32x4*)&Hs[n * 64 + tj * 4];
#pragma unroll
        for (int ii = 0; ii < 4; ++ii)
#pragma unroll
            for (int jj = 0; jj < 4; ++jj)
                acc[ii][jj] += cv[ii] * hv[jj];
    }
#pragma unroll
    for (int ii = 0; ii < 4; ++ii) {
        const int t = ti * 4 + ii;
        const float e = sEp[t];
        us4* yp = (us4*)&ybuf[(rowg0 + t) * DINNER + h * 64 + tj * 4];
        us4 y = *yp, o;
#pragma unroll
        for (int jj = 0; jj < 4; ++jj)
            o[jj] = f2bf(bf2f(y[jj]) + acc[ii][jj] * e);
        *yp = o;
    }
}

// ---------------- gate (y * silu(z)) + RMSNorm -> bf16 ----------------
__global__ __launch_bounds__(256) void gatenorm_kernel(const ushort_t* __restrict__ ybuf,
                                                       const ushort_t* __restrict__ zx,
                                                       const float* __restrict__ norm_w,
                                                       ushort_t* __restrict__ gbuf) {
    const int row = blockIdx.x;
    const int tid = threadIdx.x;
    short8 yv = *(const short8*)(ybuf + (size_t)row * DINNER + tid * 8);
    short8 zv = *(const short8*)(zx + (size_t)row * LDZX + tid * 8);
    float g[8];
    float ss = 0.f;
#pragma unroll
    for (int i = 0; i < 8; ++i) {
        float y = bf2f((ushort_t)yv[i]);
        float z = bf2f((ushort_t)zv[i]);
        float sz = z / (1.f + expf(-z));
        float gg = y * sz;
        g[i] = gg;
        ss += gg * gg;
    }
#pragma unroll
    for (int o = 32; o > 0; o >>= 1) ss += __shfl_xor(ss, o);
    __shared__ float wsum[4];
    if ((tid & 63) == 0) wsum[tid >> 6] = ss;
    __syncthreads();
    float tot = wsum[0] + wsum[1] + wsum[2] + wsum[3];
    float scale = rsqrtf(tot * (1.0f / (float)DINNER) + 1e-5f);
    short8 o8;
#pragma unroll
    for (int i = 0; i < 8; ++i)
        o8[i] = (short)f2bf(g[i] * scale * norm_w[tid * 8 + i]);
    *(short8*)(gbuf + (size_t)row * DINNER + tid * 8) = o8;
}

// ---------------- launch ----------------
extern "C" void kernel_launch(void* const* d_in, const int* in_sizes, int n_in,
                              void* d_out, int out_size, void* d_ws, size_t ws_size,
                              hipStream_t stream) {
    const float* x          = (const float*)d_in[0];
    const float* in_proj_w  = (const float*)d_in[1];
    const float* conv_w     = (const float*)d_in[2];
    const float* conv_b     = (const float*)d_in[3];
    const float* dt_bias    = (const float*)d_in[4];
    const float* A_log      = (const float*)d_in[5];
    const float* Dvec       = (const float*)d_in[6];
    const float* norm_w     = (const float*)d_in[7];
    const float* out_proj_w = (const float*)d_in[8];
    float* out = (float*)d_out;

    char* ws = (char*)d_ws;
    size_t off = 0;
    ushort_t* owbf  = (ushort_t*)(ws + off); off += (size_t)KDIM * DINNER * 2;     // 4.2 MB
    ushort_t* zx    = (ushort_t*)(ws + off); off += (size_t)NROWS * LDZX * 2;      // 71.3 MB
    ushort_t* cvb   = (ushort_t*)(ws + off); off += (size_t)NROWS * DCONVD * 2;    // 35.7 MB
    float*    dtb   = (float*)(ws + off);    off += (size_t)NROWS * NHEADS * 4;    // 1.05 MB
    float*    expPb = (float*)(ws + off);    off += (size_t)128 * L_SEQ * 4;       // 1.05 MB
    ushort_t* ybuf  = (ushort_t*)(ws + off); off += (size_t)NROWS * DINNER * 2;    // 33.6 MB
    // tail region (33.6 MB), time-multiplexed:
    //   stage 1: xbf (16.8) + wbf (8.9)     — dead after GEMM1
    //   stage 2: Gbuf -> (in-place) hstates — dead after y_inter
    //   stage 3: gbuf                        — dead after GEMM2
    char* tail = ws + off;
    ushort_t* xbf  = (ushort_t*)tail;
    ushort_t* wbf  = (ushort_t*)(tail + (size_t)NROWS * KDIM * 2);
    ushort_t* Gbuf = (ushort_t*)tail;
    ushort_t* gbuf = (ushort_t*)tail;

    // casts
    cast_bf16_kernel<<<8192, 256, 0, stream>>>(x, xbf, NROWS * KDIM / 4);
    cast_pad_w_kernel<<<4352, 256, 0, stream>>>(in_proj_w, wbf);
    cast_bf16_kernel<<<2048, 256, 0, stream>>>(out_proj_w, owbf, KDIM * DINNER / 4);

    // in-proj GEMM: zx[8192][4352] (bf16)
    gemm_bt_kernel<true><<<dim3(NPROJP / 128, NROWS / 128), 256, 0, stream>>>(
        xbf, wbf, zx, KDIM, LDZX);

    // conv + silu
    conv_silu_kernel<<<dim3((DCONVD + 255) / 256, NROWS), 256, 0, stream>>>(zx, conv_w, conv_b, cvb);

    // dt
    dt_kernel<<<NROWS * NHEADS / 256, 256, 0, stream>>>(zx, dt_bias, dtb);

    // chunked scan: phase A (parallel)
    chunk_intra_kernel<<<dim3(NCHUNK, NHEADS, 4), 256, 0, stream>>>(
        cvb, dtb, A_log, Dvec, ybuf, Gbuf, expPb);
    // phase B1: elementwise state scan (in-place G -> hstates)
    state_scan_kernel<<<dim3(2, NHEADS, 4), 256, 0, stream>>>(Gbuf, expPb);
    // phase B2: inter-chunk contribution (parallel matmuls)
    y_inter_kernel<<<dim3(NCHUNK - 1, NHEADS, 4), 256, 0, stream>>>(
        cvb, expPb, Gbuf, ybuf);

    // gate + rmsnorm
    gatenorm_kernel<<<NROWS, 256, 0, stream>>>(ybuf, zx, norm_w, gbuf);

    // out-proj GEMM -> d_out (f32)
    gemm_bt_kernel<false><<<dim3(KDIM / 128, NROWS / 128), 256, 0, stream>>>(
        gbuf, owbf, out, DINNER, KDIM);
}

// Round 4
// 345.450 us; speedup vs baseline: 4.4968x; 1.2762x over previous
//
#include <hip/hip_runtime.h>
#include <stdint.h>

typedef unsigned short ushort_t;
typedef __attribute__((ext_vector_type(4))) float f32x4;
typedef __attribute__((ext_vector_type(8))) short short8;
typedef __attribute__((ext_vector_type(4))) unsigned short us4;

#define L_SEQ   2048
#define NROWS   8192          // B*L = 4*2048
#define KDIM    1024
#define DINNER  2048
#define NHEADS  32
#define DSTATE  64
#define DCONVD  2176          // D_INNER + 2*D_STATE
#define NPROJ   4256
#define NPROJP  4352          // padded to 34*128
#define LDZX    4352
#define NCHUNK  32            // L / 64

__device__ __forceinline__ float bf2f(ushort_t u) {
    union { uint32_t i; float f; } v; v.i = ((uint32_t)u) << 16; return v.f;
}
__device__ __forceinline__ ushort_t f2bf(float f) {
    uint32_t x = __float_as_uint(f);
    x += 0x7FFFu + ((x >> 16) & 1u);
    return (ushort_t)(x >> 16);
}
// XOR-swizzled ushort index into a [64][64] bf16 tile (row stride 128 B).
// Spreads stride-128B column accesses across 8 distinct 16B slots (T2 / G4).
__device__ __forceinline__ int swzi(int row, int col) {
    return row * 64 + (col ^ ((row & 7) << 3));
}

// ---------------- cast kernels ----------------
__global__ __launch_bounds__(256) void cast_bf16_kernel(const float* __restrict__ in,
                                                        ushort_t* __restrict__ out, int n4) {
    int i = blockIdx.x * 256 + threadIdx.x;
    if (i >= n4) return;
    float4 v = ((const float4*)in)[i];
    ushort4 o;
    o.x = f2bf(v.x); o.y = f2bf(v.y); o.z = f2bf(v.z); o.w = f2bf(v.w);
    ((ushort4*)out)[i] = o;
}

__global__ __launch_bounds__(256) void cast_pad_w_kernel(const float* __restrict__ w,
                                                         ushort_t* __restrict__ out) {
    int i = blockIdx.x * 256 + threadIdx.x;   // group of 4 elems
    int idx = i * 4;
    int row = idx >> 10;
    ushort4 o;
    if (row < NPROJ) {
        float4 v = ((const float4*)w)[i];
        o.x = f2bf(v.x); o.y = f2bf(v.y); o.z = f2bf(v.z); o.w = f2bf(v.w);
    } else {
        o.x = 0; o.y = 0; o.z = 0; o.w = 0;
    }
    ((ushort4*)out)[i] = o;
}

// ---------------- MFMA GEMM:  C[M][N] = A[M][K] * B[N][K]^T ----------------
__device__ __forceinline__ void async16(const void* g, void* l) {
    __builtin_amdgcn_global_load_lds((const __attribute__((address_space(1))) void*)g,
                                     (__attribute__((address_space(3))) void*)l, 16, 0, 0);
}

template<bool OUT_BF16>
__global__ __launch_bounds__(256) void gemm_bt_kernel(const ushort_t* __restrict__ A,
                                                      const ushort_t* __restrict__ B,
                                                      void* __restrict__ Cp,
                                                      const int K, const int ldc) {
    __shared__ ushort_t As[4096];   // [128][32] bf16
    __shared__ ushort_t Bs[4096];
    const int tid  = threadIdx.x;
    const int wave = tid >> 6;
    const int lane = tid & 63;
    const int llo  = lane & 15;
    const int lhi  = lane >> 4;
    const int m0 = blockIdx.y * 128;
    const int n0 = blockIdx.x * 128;
    const int wr = wave >> 1, wc = wave & 1;

    f32x4 acc[4][4];
    const f32x4 zero = {0.f, 0.f, 0.f, 0.f};
#pragma unroll
    for (int i = 0; i < 4; ++i)
#pragma unroll
        for (int j = 0; j < 4; ++j) acc[i][j] = zero;

    const int srow = tid >> 2;
    const int skq  = tid & 3;
    const ushort_t* gA = A + (size_t)(m0 + srow) * K + skq * 8;
    const ushort_t* gB = B + (size_t)(n0 + srow) * K + skq * 8;
    ushort_t* lA0 = As + wave * 512;
    ushort_t* lA1 = As + 2048 + wave * 512;
    ushort_t* lB0 = Bs + wave * 512;
    ushort_t* lB1 = Bs + 2048 + wave * 512;
    const size_t rstep = (size_t)64 * K;

    const ushort_t* pa = As + (wr * 64 + llo) * 32 + lhi * 8;
    const ushort_t* pb = Bs + (wc * 64 + llo) * 32 + lhi * 8;

    for (int k0 = 0; k0 < K; k0 += 32) {
        __syncthreads();
        async16(gA + k0, lA0);
        async16(gA + rstep + k0, lA1);
        async16(gB + k0, lB0);
        async16(gB + rstep + k0, lB1);
        __syncthreads();
        short8 af[4], bfr[4];
#pragma unroll
        for (int i = 0; i < 4; ++i) af[i]  = *(const short8*)(pa + i * 512);
#pragma unroll
        for (int j = 0; j < 4; ++j) bfr[j] = *(const short8*)(pb + j * 512);
#pragma unroll
        for (int i = 0; i < 4; ++i)
#pragma unroll
            for (int j = 0; j < 4; ++j)
                acc[i][j] = __builtin_amdgcn_mfma_f32_16x16x32_bf16(af[i], bfr[j], acc[i][j], 0, 0, 0);
    }

#pragma unroll
    for (int i = 0; i < 4; ++i)
#pragma unroll
        for (int j = 0; j < 4; ++j) {
            const int col = n0 + wc * 64 + j * 16 + llo;
            const int rowb = m0 + wr * 64 + i * 16 + lhi * 4;
#pragma unroll
            for (int r = 0; r < 4; ++r) {
                if (OUT_BF16) {
                    ((ushort_t*)Cp)[(size_t)(rowb + r) * ldc + col] = f2bf(acc[i][j][r]);
                } else {
                    ((float*)Cp)[(size_t)(rowb + r) * ldc + col] = acc[i][j][r];
                }
            }
        }
}

// ---------------- conv (4-tap causal) + SiLU ----------------
__global__ __launch_bounds__(256) void conv_silu_kernel(const ushort_t* __restrict__ zx,
                                                        const float* __restrict__ conv_w,
                                                        const float* __restrict__ conv_b,
                                                        ushort_t* __restrict__ convout) {
    const int c = blockIdx.x * 256 + threadIdx.x;
    const int row = blockIdx.y;
    if (c >= DCONVD) return;
    const int l = row & (L_SEQ - 1);
    float acc = conv_b[c];
#pragma unroll
    for (int k = 0; k < 4; ++k) {
        int ll = l - 3 + k;
        if (ll >= 0)
            acc += bf2f(zx[(size_t)(row - 3 + k) * LDZX + DINNER + c]) * conv_w[c * 4 + k];
    }
    float s = acc / (1.f + expf(-acc));
    convout[(size_t)row * DCONVD + c] = f2bf(s);
}

// ---------------- dt = softplus(raw + bias) ----------------
__global__ __launch_bounds__(256) void dt_kernel(const ushort_t* __restrict__ zx,
                                                 const float* __restrict__ dt_bias,
                                                 float* __restrict__ dtb) {
    int idx = blockIdx.x * 256 + threadIdx.x;   // NROWS*32
    int row = idx >> 5;
    int h = idx & 31;
    float v = bf2f(zx[(size_t)row * LDZX + NPROJ - NHEADS + h]) + dt_bias[h];
    dtb[idx] = (v > 20.f) ? v : log1pf(expf(v));
}

// ---------------- Phase A (MFMA): per-chunk intra output + chunk state G ----------------
// One WG per (chunk c, head h, batch b). Three 64x64x64 matmuls on the matrix pipe:
//   S  = C.B^T (masked: *exp(Pi-Pj)*dt_j for j<=i, +D on diag)   [MFMA 1]
//   Y  = S.X                                   -> ybuf bf16      [MFMA 2]
//   G^T[p][n] = sum_t (w_t B[t][n]) X[t][p]    -> Gbuf bf16      [MFMA 3]
__global__ __launch_bounds__(256) void chunk_intra_kernel(
    const ushort_t* __restrict__ cvb, const float* __restrict__ dtb,
    const float* __restrict__ A_log, const float* __restrict__ Dvec,
    ushort_t* __restrict__ ybuf, ushort_t* __restrict__ Gbuf,
    float* __restrict__ expPb)
{
    const int c = blockIdx.x, h = blockIdx.y, b = blockIdx.z;
    const int tid = threadIdx.x;
    const int wv = tid >> 6, lane = tid & 63;
    const int lr = lane & 15, lk = lane >> 4;

    __shared__ __align__(16) ushort_t Cs[4096];  // [t][n] swz
    __shared__ __align__(16) ushort_t Bs[4096];  // [t][n] swz
    __shared__ __align__(16) ushort_t Xt[4096];  // [p][t] swz
    __shared__ __align__(16) ushort_t Ss[4096];  // [i][j] swz (masked S, bf16)
    __shared__ __align__(16) ushort_t Bw[4096];  // [n][t] swz (B^T * w_t)
    __shared__ float sP[64], sdt[64], sWf[64];

    const int t4 = tid >> 2, qq = tid & 3;
    const size_t rowg0 = (size_t)b * L_SEQ + c * 64;
    const ushort_t* rowp = cvb + (rowg0 + t4) * DCONVD;

    short8 rb0 = *(const short8*)(rowp + DINNER + qq * 16);
    short8 rb1 = *(const short8*)(rowp + DINNER + qq * 16 + 8);
    short8 rc0 = *(const short8*)(rowp + DINNER + DSTATE + qq * 16);
    short8 rc1 = *(const short8*)(rowp + DINNER + DSTATE + qq * 16 + 8);
    short8 rx0 = *(const short8*)(rowp + h * 64 + qq * 16);
    short8 rx1 = *(const short8*)(rowp + h * 64 + qq * 16 + 8);

    // stage Cs, Bs (row-major, 16B pieces keep uniform swizzle)
    *(short8*)&Cs[swzi(t4, qq * 16)]     = rc0;
    *(short8*)&Cs[swzi(t4, qq * 16 + 8)] = rc1;
    *(short8*)&Bs[swzi(t4, qq * 16)]     = rb0;
    *(short8*)&Bs[swzi(t4, qq * 16 + 8)] = rb1;
    // stage X transposed: Xt[p][t]
#pragma unroll
    for (int k = 0; k < 8; ++k) {
        Xt[swzi(qq * 16 + k, t4)]     = (ushort_t)rx0[k];
        Xt[swzi(qq * 16 + 8 + k, t4)] = (ushort_t)rx1[k];
    }
    if (tid < 64) {
        float dt = dtb[(rowg0 + tid) * NHEADS + h];
        float A = -__expf(A_log[h]);
        float P = dt * A;
#pragma unroll
        for (int off = 1; off < 64; off <<= 1) {
            float o = __shfl_up(P, off);
            if (tid >= off) P += o;
        }
        sP[tid] = P;
        sdt[tid] = dt;
        float P63 = __shfl(P, 63);
        sWf[tid] = __expf(P63 - P) * dt;
        expPb[(size_t)(b * NHEADS + h) * L_SEQ + c * 64 + tid] = __expf(P);
    }
    __syncthreads();

    // stage Bw[n][t] = B[t][n] * w_t  (needs sWf)
    {
        const float w = sWf[t4];
#pragma unroll
        for (int k = 0; k < 8; ++k) {
            Bw[swzi(qq * 16 + k, t4)]     = f2bf(bf2f((ushort_t)rb0[k]) * w);
            Bw[swzi(qq * 16 + 8 + k, t4)] = f2bf(bf2f((ushort_t)rb1[k]) * w);
        }
    }

    // ---- MFMA 1: S = C.B^T  (wave wv owns rows i = wv*16..+15, 4 col tiles) ----
    const float Dh = Dvec[h];
    {
        short8 a0 = *(const short8*)&Cs[swzi(wv * 16 + lr, lk * 8)];
        short8 a1 = *(const short8*)&Cs[swzi(wv * 16 + lr, 32 + lk * 8)];
        f32x4 acc[4];
        const f32x4 zero = {0.f, 0.f, 0.f, 0.f};
#pragma unroll
        for (int nj = 0; nj < 4; ++nj) {
            short8 b0 = *(const short8*)&Bs[swzi(nj * 16 + lr, lk * 8)];
            short8 b1 = *(const short8*)&Bs[swzi(nj * 16 + lr, 32 + lk * 8)];
            acc[nj] = __builtin_amdgcn_mfma_f32_16x16x32_bf16(a0, b0, zero, 0, 0, 0);
            acc[nj] = __builtin_amdgcn_mfma_f32_16x16x32_bf16(a1, b1, acc[nj], 0, 0, 0);
        }
        // mask/scale in C/D layout: i = wv*16 + lk*4 + r, j = nj*16 + lr
#pragma unroll
        for (int r = 0; r < 4; ++r) {
            const int i = wv * 16 + lk * 4 + r;
            const float Pi = sP[i];
#pragma unroll
            for (int nj = 0; nj < 4; ++nj) {
                const int j = nj * 16 + lr;
                float s = 0.f;
                if (j <= i) s = acc[nj][r] * __expf(Pi - sP[j]) * sdt[j];
                if (j == i) s += Dh;
                Ss[swzi(i, j)] = f2bf(s);
            }
        }
    }
    __syncthreads();

    // ---- MFMA 2: Y = S.X  -> ybuf ----
    {
        short8 a0 = *(const short8*)&Ss[swzi(wv * 16 + lr, lk * 8)];
        short8 a1 = *(const short8*)&Ss[swzi(wv * 16 + lr, 32 + lk * 8)];
        const f32x4 zero = {0.f, 0.f, 0.f, 0.f};
#pragma unroll
        for (int np = 0; np < 4; ++np) {
            short8 b0 = *(const short8*)&Xt[swzi(np * 16 + lr, lk * 8)];
            short8 b1 = *(const short8*)&Xt[swzi(np * 16 + lr, 32 + lk * 8)];
            f32x4 acc = __builtin_amdgcn_mfma_f32_16x16x32_bf16(a0, b0, zero, 0, 0, 0);
            acc = __builtin_amdgcn_mfma_f32_16x16x32_bf16(a1, b1, acc, 0, 0, 0);
#pragma unroll
            for (int r = 0; r < 4; ++r) {
                const int i = wv * 16 + lk * 4 + r;
                const int p = np * 16 + lr;
                ybuf[(rowg0 + i) * DINNER + (size_t)h * 64 + p] = f2bf(acc[r]);
            }
        }
    }

    // ---- MFMA 3: G^T[p][n] = Xt . Bw^T -> Gbuf ([p][n] layout) ----
    {
        short8 a0 = *(const short8*)&Xt[swzi(wv * 16 + lr, lk * 8)];
        short8 a1 = *(const short8*)&Xt[swzi(wv * 16 + lr, 32 + lk * 8)];
        const f32x4 zero = {0.f, 0.f, 0.f, 0.f};
        const size_t gbase = ((size_t)((b * NHEADS + h) * NCHUNK + c)) << 12;
#pragma unroll
        for (int nt = 0; nt < 4; ++nt) {
            short8 b0 = *(const short8*)&Bw[swzi(nt * 16 + lr, lk * 8)];
            short8 b1 = *(const short8*)&Bw[swzi(nt * 16 + lr, 32 + lk * 8)];
            f32x4 acc = __builtin_amdgcn_mfma_f32_16x16x32_bf16(a0, b0, zero, 0, 0, 0);
            acc = __builtin_amdgcn_mfma_f32_16x16x32_bf16(a1, b1, acc, 0, 0, 0);
#pragma unroll
            for (int r = 0; r < 4; ++r) {
                const int p = wv * 16 + lk * 4 + r;
                const int n = nt * 16 + lr;
                Gbuf[gbase + p * 64 + n] = f2bf(acc[r]);
            }
        }
    }
}

// ---------------- Phase B1: elementwise chunk-state scan (in-place G -> hstates) ----------------
// GH[(bh*32+c)*4096 + e]: on entry G^T (chunk increment, [p][n]), on exit state ENTERING
// chunk c (same layout). Serial chain is 32 register FMAs per element.
__global__ __launch_bounds__(256) void state_scan_kernel(
    ushort_t* __restrict__ GH, const float* __restrict__ expPb)
{
    const int half = blockIdx.x, h = blockIdx.y, b = blockIdx.z;
    const int bh = b * NHEADS + h;
    const int e0 = half * 2048 + threadIdx.x * 8;
    ushort_t* base = GH + ((size_t)bh << 17);
    const float* ep = expPb + (size_t)bh * L_SEQ;

    float hr[8];
#pragma unroll
    for (int k = 0; k < 8; ++k) hr[k] = 0.f;

    short8 g = *(const short8*)(base + e0);
    float Ec = ep[63];
    for (int c = 0; c < NCHUNK; ++c) {
        short8 gn = g; float En = 0.f;
        if (c + 1 < NCHUNK) {
            gn = *(const short8*)(base + ((size_t)(c + 1) << 12) + e0);
            En = ep[(c + 1) * 64 + 63];
        }
        short8 o;
#pragma unroll
        for (int k = 0; k < 8; ++k) o[k] = (short)f2bf(hr[k]);
        *(short8*)(base + ((size_t)c << 12) + e0) = o;
#pragma unroll
        for (int k = 0; k < 8; ++k) hr[k] = hr[k] * Ec + bf2f((ushort_t)g[k]);
        g = gn; Ec = En;
    }
}

// ---------------- Phase B2 (MFMA): y_inter[t][p] = expP[t] * sum_n C[t][n] h[n][p] ----------------
// h stored transposed ([p][n]) by chunk_intra — exactly the MFMA B-operand layout.
__global__ __launch_bounds__(256) void y_inter_kernel(
    const ushort_t* __restrict__ cvb, const float* __restrict__ expPb,
    const ushort_t* __restrict__ hst, ushort_t* __restrict__ ybuf)
{
    const int c = blockIdx.x + 1, h = blockIdx.y, b = blockIdx.z;
    const int tid = threadIdx.x;
    const int wv = tid >> 6, lane = tid & 63;
    const int lr = lane & 15, lk = lane >> 4;
    const int bh = b * NHEADS + h;

    __shared__ __align__(16) ushort_t Cs[4096];  // [t][n] swz
    __shared__ __align__(16) ushort_t Hp[4096];  // [p][n] swz
    __shared__ float sEp[64];

    const int t4 = tid >> 2, qq = tid & 3;
    const size_t rowg0 = (size_t)b * L_SEQ + c * 64;
    {
        const ushort_t* rp = cvb + (rowg0 + t4) * DCONVD + DINNER + DSTATE + qq * 16;
        *(short8*)&Cs[swzi(t4, qq * 16)]     = *(const short8*)rp;
        *(short8*)&Cs[swzi(t4, qq * 16 + 8)] = *(const short8*)(rp + 8);
        const ushort_t* hr = hst + (((size_t)(bh * NCHUNK + c)) << 12) + t4 * 64 + qq * 16;
        *(short8*)&Hp[swzi(t4, qq * 16)]     = *(const short8*)hr;
        *(short8*)&Hp[swzi(t4, qq * 16 + 8)] = *(const short8*)(hr + 8);
    }
    if (tid < 64) sEp[tid] = expPb[(size_t)bh * L_SEQ + c * 64 + tid];
    __syncthreads();

    short8 a0 = *(const short8*)&Cs[swzi(wv * 16 + lr, lk * 8)];
    short8 a1 = *(const short8*)&Cs[swzi(wv * 16 + lr, 32 + lk * 8)];
    const f32x4 zero = {0.f, 0.f, 0.f, 0.f};
#pragma unroll
    for (int np = 0; np < 4; ++np) {
        short8 b0 = *(const short8*)&Hp[swzi(np * 16 + lr, lk * 8)];
        short8 b1 = *(const short8*)&Hp[swzi(np * 16 + lr, 32 + lk * 8)];
        f32x4 acc = __builtin_amdgcn_mfma_f32_16x16x32_bf16(a0, b0, zero, 0, 0, 0);
        acc = __builtin_amdgcn_mfma_f32_16x16x32_bf16(a1, b1, acc, 0, 0, 0);
#pragma unroll
        for (int r = 0; r < 4; ++r) {
            const int t = wv * 16 + lk * 4 + r;
            const int p = np * 16 + lr;
            ushort_t* yp = &ybuf[(rowg0 + t) * DINNER + (size_t)h * 64 + p];
            *yp = f2bf(bf2f(*yp) + acc[r] * sEp[t]);
        }
    }
}

// ---------------- gate (y * silu(z)) + RMSNorm -> bf16 ----------------
__global__ __launch_bounds__(256) void gatenorm_kernel(const ushort_t* __restrict__ ybuf,
                                                       const ushort_t* __restrict__ zx,
                                                       const float* __restrict__ norm_w,
                                                       ushort_t* __restrict__ gbuf) {
    const int row = blockIdx.x;
    const int tid = threadIdx.x;
    short8 yv = *(const short8*)(ybuf + (size_t)row * DINNER + tid * 8);
    short8 zv = *(const short8*)(zx + (size_t)row * LDZX + tid * 8);
    float g[8];
    float ss = 0.f;
#pragma unroll
    for (int i = 0; i < 8; ++i) {
        float y = bf2f((ushort_t)yv[i]);
        float z = bf2f((ushort_t)zv[i]);
        float sz = z / (1.f + expf(-z));
        float gg = y * sz;
        g[i] = gg;
        ss += gg * gg;
    }
#pragma unroll
    for (int o = 32; o > 0; o >>= 1) ss += __shfl_xor(ss, o);
    __shared__ float wsum[4];
    if ((tid & 63) == 0) wsum[tid >> 6] = ss;
    __syncthreads();
    float tot = wsum[0] + wsum[1] + wsum[2] + wsum[3];
    float scale = rsqrtf(tot * (1.0f / (float)DINNER) + 1e-5f);
    short8 o8;
#pragma unroll
    for (int i = 0; i < 8; ++i)
        o8[i] = (short)f2bf(g[i] * scale * norm_w[tid * 8 + i]);
    *(short8*)(gbuf + (size_t)row * DINNER + tid * 8) = o8;
}

// ---------------- launch ----------------
extern "C" void kernel_launch(void* const* d_in, const int* in_sizes, int n_in,
                              void* d_out, int out_size, void* d_ws, size_t ws_size,
                              hipStream_t stream) {
    const float* x          = (const float*)d_in[0];
    const float* in_proj_w  = (const float*)d_in[1];
    const float* conv_w     = (const float*)d_in[2];
    const float* conv_b     = (const float*)d_in[3];
    const float* dt_bias    = (const float*)d_in[4];
    const float* A_log      = (const float*)d_in[5];
    const float* Dvec       = (const float*)d_in[6];
    const float* norm_w     = (const float*)d_in[7];
    const float* out_proj_w = (const float*)d_in[8];
    float* out = (float*)d_out;

    char* ws = (char*)d_ws;
    size_t off = 0;
    ushort_t* owbf  = (ushort_t*)(ws + off); off += (size_t)KDIM * DINNER * 2;     // 4.2 MB
    ushort_t* zx    = (ushort_t*)(ws + off); off += (size_t)NROWS * LDZX * 2;      // 71.3 MB
    ushort_t* cvb   = (ushort_t*)(ws + off); off += (size_t)NROWS * DCONVD * 2;    // 35.7 MB
    float*    dtb   = (float*)(ws + off);    off += (size_t)NROWS * NHEADS * 4;    // 1.05 MB
    float*    expPb = (float*)(ws + off);    off += (size_t)128 * L_SEQ * 4;       // 1.05 MB
    ushort_t* ybuf  = (ushort_t*)(ws + off); off += (size_t)NROWS * DINNER * 2;    // 33.6 MB
    // tail region (33.6 MB), time-multiplexed:
    //   stage 1: xbf (16.8) + wbf (8.9)     — dead after GEMM1
    //   stage 2: Gbuf -> (in-place) hstates — dead after y_inter
    //   stage 3: gbuf                        — dead after GEMM2
    char* tail = ws + off;
    ushort_t* xbf  = (ushort_t*)tail;
    ushort_t* wbf  = (ushort_t*)(tail + (size_t)NROWS * KDIM * 2);
    ushort_t* Gbuf = (ushort_t*)tail;
    ushort_t* gbuf = (ushort_t*)tail;

    // casts
    cast_bf16_kernel<<<8192, 256, 0, stream>>>(x, xbf, NROWS * KDIM / 4);
    cast_pad_w_kernel<<<4352, 256, 0, stream>>>(in_proj_w, wbf);
    cast_bf16_kernel<<<2048, 256, 0, stream>>>(out_proj_w, owbf, KDIM * DINNER / 4);

    // in-proj GEMM: zx[8192][4352] (bf16)
    gemm_bt_kernel<true><<<dim3(NPROJP / 128, NROWS / 128), 256, 0, stream>>>(
        xbf, wbf, zx, KDIM, LDZX);

    // conv + silu
    conv_silu_kernel<<<dim3((DCONVD + 255) / 256, NROWS), 256, 0, stream>>>(zx, conv_w, conv_b, cvb);

    // dt
    dt_kernel<<<NROWS * NHEADS / 256, 256, 0, stream>>>(zx, dt_bias, dtb);

    // chunked scan: phase A (parallel, MFMA)
    chunk_intra_kernel<<<dim3(NCHUNK, NHEADS, 4), 256, 0, stream>>>(
        cvb, dtb, A_log, Dvec, ybuf, Gbuf, expPb);
    // phase B1: elementwise state scan (in-place G -> hstates)
    state_scan_kernel<<<dim3(2, NHEADS, 4), 256, 0, stream>>>(Gbuf, expPb);
    // phase B2: inter-chunk contribution (parallel MFMA matmuls)
    y_inter_kernel<<<dim3(NCHUNK - 1, NHEADS, 4), 256, 0, stream>>>(
        cvb, expPb, Gbuf, ybuf);

    // gate + rmsnorm
    gatenorm_kernel<<<NROWS, 256, 0, stream>>>(ybuf, zx, norm_w, gbuf);

    // out-proj GEMM -> d_out (f32)
    gemm_bt_kernel<false><<<dim3(KDIM / 128, NROWS / 128), 256, 0, stream>>>(
        gbuf, owbf, out, DINNER, KDIM);
}

// Round 5
// 340.920 us; speedup vs baseline: 4.5565x; 1.0133x over previous
//
#include <hip/hip_runtime.h>
#include <stdint.h>

typedef unsigned short ushort_t;
typedef __attribute__((ext_vector_type(4))) float f32x4;
typedef __attribute__((ext_vector_type(8))) short short8;
typedef __attribute__((ext_vector_type(4))) unsigned short us4;

#define L_SEQ   2048
#define NROWS   8192          // B*L = 4*2048
#define KDIM    1024
#define DINNER  2048
#define NHEADS  32
#define DSTATE  64
#define DCONVD  2176          // D_INNER + 2*D_STATE
#define NPROJ   4256
#define NPROJP  4352          // padded to 34*128 (= 17*256)
#define LDZX    4352
#define NCHUNK  32            // L / 64

__device__ __forceinline__ float bf2f(ushort_t u) {
    union { uint32_t i; float f; } v; v.i = ((uint32_t)u) << 16; return v.f;
}
__device__ __forceinline__ ushort_t f2bf(float f) {
    uint32_t x = __float_as_uint(f);
    x += 0x7FFFu + ((x >> 16) & 1u);
    return (ushort_t)(x >> 16);
}
__device__ __forceinline__ int swzi(int row, int col) {
    return row * 64 + (col ^ ((row & 7) << 3));
}

// ---------------- cast kernels ----------------
__global__ __launch_bounds__(256) void cast_bf16_kernel(const float* __restrict__ in,
                                                        ushort_t* __restrict__ out, int n4) {
    int i = blockIdx.x * 256 + threadIdx.x;
    if (i >= n4) return;
    float4 v = ((const float4*)in)[i];
    ushort4 o;
    o.x = f2bf(v.x); o.y = f2bf(v.y); o.z = f2bf(v.z); o.w = f2bf(v.w);
    ((ushort4*)out)[i] = o;
}

__global__ __launch_bounds__(256) void cast_pad_w_kernel(const float* __restrict__ w,
                                                         ushort_t* __restrict__ out) {
    int i = blockIdx.x * 256 + threadIdx.x;   // group of 4 elems
    int idx = i * 4;
    int row = idx >> 10;
    ushort4 o;
    if (row < NPROJ) {
        float4 v = ((const float4*)w)[i];
        o.x = f2bf(v.x); o.y = f2bf(v.y); o.z = f2bf(v.z); o.w = f2bf(v.w);
    } else {
        o.x = 0; o.y = 0; o.z = 0; o.w = 0;
    }
    ((ushort4*)out)[i] = o;
}

__device__ __forceinline__ void async16(const void* g, void* l) {
    __builtin_amdgcn_global_load_lds((const __attribute__((address_space(1))) void*)g,
                                     (__attribute__((address_space(3))) void*)l, 16, 0, 0);
}

// ---------------- 256x256 8-phase GEMM (in-proj): C[8192][4352] = A[8192][1024] * B[4352][1024]^T
// 8 waves (2M x 4N), BK=64, dbuf LDS 128 KiB, counted vmcnt (never 0 mid-loop),
// T2 swizzle via inverse-swizzled global source + swizzled ds_read (rule #21).
__global__ __launch_bounds__(512, 1) void gemm256_kernel(const ushort_t* __restrict__ A,
                                                         const ushort_t* __restrict__ B,
                                                         ushort_t* __restrict__ C) {
    __shared__ ushort_t lds[2][2][2][8192];  // [dbuf][mat A/B][half][128 rows * 64 cols]
    const int tid = threadIdx.x;
    const int w = tid >> 6, l = tid & 63;
    const int lr = l & 15, lk = l >> 4;
    const int wm = w >> 2, wn = w & 3;

    // XCD-bijective block swizzle: 544 WGs = 8 * 68
    const int lin = blockIdx.x;
    const int swz = (lin & 7) * 68 + (lin >> 3);
    const int nt = swz % 17, mt = swz / 17;
    const int m0 = mt * 256, n0 = nt * 256;

    // staging constants: slot s = r*512 + tid -> LDS (row = s>>3, c16 = s&7);
    // source fetches global c16 ^ (row&7) so that swizzled reads see linear K.
    const int row0 = tid >> 3,          c0 = (tid & 7) ^ (row0 & 7);
    const int row1 = (512 + tid) >> 3,  c1 = ((512 + tid) & 7) ^ (row1 & 7);

    f32x4 acc[8][4];
    const f32x4 zero = {0.f, 0.f, 0.f, 0.f};
#pragma unroll
    for (int i = 0; i < 8; ++i)
#pragma unroll
        for (int j = 0; j < 4; ++j) acc[i][j] = zero;

#define STAGE256(d_, mat_, h_, ktn_) do {                                              \
        const ushort_t* gb_ = ((mat_) == 0 ? A + (size_t)(m0 + (h_) * 128) * KDIM      \
                                           : B + (size_t)(n0 + (h_) * 128) * KDIM)     \
                              + (ktn_) * 64;                                           \
        async16(gb_ + (size_t)row0 * KDIM + c0 * 8, &lds[d_][mat_][h_][w * 512]);      \
        async16(gb_ + (size_t)row1 * KDIM + c1 * 8, &lds[d_][mat_][h_][4096 + w * 512]);\
    } while (0)

    // prologue: stage kt=0 (4 half-tiles, 8 loads/wave) into dbuf 0
    STAGE256(0, 0, 0, 0);
    STAGE256(0, 1, 0, 0);
    STAGE256(0, 0, 1, 0);
    STAGE256(0, 1, 1, 0);

    const int NKT = KDIM / 64;   // 16
    for (int kt = 0; kt < NKT; ++kt) {
        const int d = kt & 1;
        const ushort_t* Ah = &lds[d][0][wm][0];
        const ushort_t* Bh = &lds[d][1][wn >> 1][0];
        const int bcol0 = (wn & 1) * 64;
#pragma unroll
        for (int q = 0; q < 4; ++q) {
            const int qm = q >> 1, qn = q & 1;
            if (kt + 1 < NKT) {
                // q0:A-half0, q1:B-half0, q2:A-half1, q3:B-half1 of kt+1
                STAGE256(d ^ 1, (q & 1), (q >> 1), kt + 1);
            }
            if (q == 0) {
                if (kt + 1 < NKT) asm volatile("s_waitcnt vmcnt(2)" ::: "memory");
                else              asm volatile("s_waitcnt vmcnt(0)" ::: "memory");
            }
            __builtin_amdgcn_s_barrier();
            asm volatile("" ::: "memory");
            short8 af[4][2], bfv[2][2];
#pragma unroll
            for (int fr = 0; fr < 4; ++fr) {
                const int ar = qm * 64 + fr * 16 + lr;
                const int x7 = ar & 7;
#pragma unroll
                for (int ks = 0; ks < 2; ++ks) {
                    const int k16 = ks * 4 + lk;
                    af[fr][ks] = *(const short8*)&Ah[ar * 64 + ((k16 ^ x7) << 3)];
                }
            }
#pragma unroll
            for (int fc = 0; fc < 2; ++fc) {
                const int br = bcol0 + qn * 32 + fc * 16 + lr;
                const int x7 = br & 7;
#pragma unroll
                for (int ks = 0; ks < 2; ++ks) {
                    const int k16 = ks * 4 + lk;
                    bfv[fc][ks] = *(const short8*)&Bh[br * 64 + ((k16 ^ x7) << 3)];
                }
            }
            __builtin_amdgcn_s_setprio(1);
#pragma unroll
            for (int ks = 0; ks < 2; ++ks)
#pragma unroll
                for (int fr = 0; fr < 4; ++fr)
#pragma unroll
                    for (int fc = 0; fc < 2; ++fc)
                        acc[qm * 4 + fr][qn * 2 + fc] = __builtin_amdgcn_mfma_f32_16x16x32_bf16(
                            af[fr][ks], bfv[fc][ks], acc[qm * 4 + fr][qn * 2 + fc], 0, 0, 0);
            __builtin_amdgcn_s_setprio(0);
            asm volatile("" ::: "memory");
            __builtin_amdgcn_s_barrier();
        }
    }

    // epilogue: C write (bf16, ldc = LDZX)
#pragma unroll
    for (int fr2 = 0; fr2 < 8; ++fr2)
#pragma unroll
        for (int fc2 = 0; fc2 < 4; ++fc2) {
            const int col = n0 + wn * 64 + fc2 * 16 + lr;
            const int rowb = m0 + wm * 128 + fr2 * 16 + lk * 4;
#pragma unroll
            for (int r = 0; r < 4; ++r)
                C[(size_t)(rowb + r) * LDZX + col] = f2bf(acc[fr2][fc2][r]);
        }
#undef STAGE256
}

// ---------------- 128x128 MFMA GEMM (out-proj):  C[M][N] = A[M][K] * B[N][K]^T ----------------
template<bool OUT_BF16>
__global__ __launch_bounds__(256) void gemm_bt_kernel(const ushort_t* __restrict__ A,
                                                      const ushort_t* __restrict__ B,
                                                      void* __restrict__ Cp,
                                                      const int K, const int ldc) {
    __shared__ ushort_t As[4096];   // [128][32] bf16
    __shared__ ushort_t Bs[4096];
    const int tid  = threadIdx.x;
    const int wave = tid >> 6;
    const int lane = tid & 63;
    const int llo  = lane & 15;
    const int lhi  = lane >> 4;
    const int m0 = blockIdx.y * 128;
    const int n0 = blockIdx.x * 128;
    const int wr = wave >> 1, wc = wave & 1;

    f32x4 acc[4][4];
    const f32x4 zero = {0.f, 0.f, 0.f, 0.f};
#pragma unroll
    for (int i = 0; i < 4; ++i)
#pragma unroll
        for (int j = 0; j < 4; ++j) acc[i][j] = zero;

    const int srow = tid >> 2;
    const int skq  = tid & 3;
    const ushort_t* gA = A + (size_t)(m0 + srow) * K + skq * 8;
    const ushort_t* gB = B + (size_t)(n0 + srow) * K + skq * 8;
    ushort_t* lA0 = As + wave * 512;
    ushort_t* lA1 = As + 2048 + wave * 512;
    ushort_t* lB0 = Bs + wave * 512;
    ushort_t* lB1 = Bs + 2048 + wave * 512;
    const size_t rstep = (size_t)64 * K;

    const ushort_t* pa = As + (wr * 64 + llo) * 32 + lhi * 8;
    const ushort_t* pb = Bs + (wc * 64 + llo) * 32 + lhi * 8;

    for (int k0 = 0; k0 < K; k0 += 32) {
        __syncthreads();
        async16(gA + k0, lA0);
        async16(gA + rstep + k0, lA1);
        async16(gB + k0, lB0);
        async16(gB + rstep + k0, lB1);
        __syncthreads();
        short8 af[4], bfr[4];
#pragma unroll
        for (int i = 0; i < 4; ++i) af[i]  = *(const short8*)(pa + i * 512);
#pragma unroll
        for (int j = 0; j < 4; ++j) bfr[j] = *(const short8*)(pb + j * 512);
#pragma unroll
        for (int i = 0; i < 4; ++i)
#pragma unroll
            for (int j = 0; j < 4; ++j)
                acc[i][j] = __builtin_amdgcn_mfma_f32_16x16x32_bf16(af[i], bfr[j], acc[i][j], 0, 0, 0);
    }

#pragma unroll
    for (int i = 0; i < 4; ++i)
#pragma unroll
        for (int j = 0; j < 4; ++j) {
            const int col = n0 + wc * 64 + j * 16 + llo;
            const int rowb = m0 + wr * 64 + i * 16 + lhi * 4;
#pragma unroll
            for (int r = 0; r < 4; ++r) {
                if (OUT_BF16) {
                    ((ushort_t*)Cp)[(size_t)(rowb + r) * ldc + col] = f2bf(acc[i][j][r]);
                } else {
                    ((float*)Cp)[(size_t)(rowb + r) * ldc + col] = acc[i][j][r];
                }
            }
        }
}

// ---------------- conv (4-tap causal) + SiLU ----------------
__global__ __launch_bounds__(256) void conv_silu_kernel(const ushort_t* __restrict__ zx,
                                                        const float* __restrict__ conv_w,
                                                        const float* __restrict__ conv_b,
                                                        ushort_t* __restrict__ convout) {
    const int c = blockIdx.x * 256 + threadIdx.x;
    const int row = blockIdx.y;
    if (c >= DCONVD) return;
    const int l = row & (L_SEQ - 1);
    float acc = conv_b[c];
#pragma unroll
    for (int k = 0; k < 4; ++k) {
        int ll = l - 3 + k;
        if (ll >= 0)
            acc += bf2f(zx[(size_t)(row - 3 + k) * LDZX + DINNER + c]) * conv_w[c * 4 + k];
    }
    float s = acc / (1.f + expf(-acc));
    convout[(size_t)row * DCONVD + c] = f2bf(s);
}

// ---------------- dt = softplus(raw + bias) ----------------
__global__ __launch_bounds__(256) void dt_kernel(const ushort_t* __restrict__ zx,
                                                 const float* __restrict__ dt_bias,
                                                 float* __restrict__ dtb) {
    int idx = blockIdx.x * 256 + threadIdx.x;   // NROWS*32
    int row = idx >> 5;
    int h = idx & 31;
    float v = bf2f(zx[(size_t)row * LDZX + NPROJ - NHEADS + h]) + dt_bias[h];
    dtb[idx] = (v > 20.f) ? v : log1pf(expf(v));
}

// ---------------- Phase A (MFMA): per-chunk intra output + chunk state G ----------------
__global__ __launch_bounds__(256) void chunk_intra_kernel(
    const ushort_t* __restrict__ cvb, const float* __restrict__ dtb,
    const float* __restrict__ A_log, const float* __restrict__ Dvec,
    ushort_t* __restrict__ ybuf, ushort_t* __restrict__ Gbuf,
    float* __restrict__ expPb)
{
    const int c = blockIdx.x, h = blockIdx.y, b = blockIdx.z;
    const int tid = threadIdx.x;
    const int wv = tid >> 6, lane = tid & 63;
    const int lr = lane & 15, lk = lane >> 4;

    __shared__ __align__(16) ushort_t Cs[4096];  // [t][n] swz
    __shared__ __align__(16) ushort_t Bs[4096];  // [t][n] swz
    __shared__ __align__(16) ushort_t Xt[4096];  // [p][t] swz
    __shared__ __align__(16) ushort_t Ss[4096];  // [i][j] swz (masked S, bf16)
    __shared__ __align__(16) ushort_t Bw[4096];  // [n][t] swz (B^T * w_t)
    __shared__ float sP[64], sdt[64], sWf[64];

    const int t4 = tid >> 2, qq = tid & 3;
    const size_t rowg0 = (size_t)b * L_SEQ + c * 64;
    const ushort_t* rowp = cvb + (rowg0 + t4) * DCONVD;

    short8 rb0 = *(const short8*)(rowp + DINNER + qq * 16);
    short8 rb1 = *(const short8*)(rowp + DINNER + qq * 16 + 8);
    short8 rc0 = *(const short8*)(rowp + DINNER + DSTATE + qq * 16);
    short8 rc1 = *(const short8*)(rowp + DINNER + DSTATE + qq * 16 + 8);
    short8 rx0 = *(const short8*)(rowp + h * 64 + qq * 16);
    short8 rx1 = *(const short8*)(rowp + h * 64 + qq * 16 + 8);

    *(short8*)&Cs[swzi(t4, qq * 16)]     = rc0;
    *(short8*)&Cs[swzi(t4, qq * 16 + 8)] = rc1;
    *(short8*)&Bs[swzi(t4, qq * 16)]     = rb0;
    *(short8*)&Bs[swzi(t4, qq * 16 + 8)] = rb1;
#pragma unroll
    for (int k = 0; k < 8; ++k) {
        Xt[swzi(qq * 16 + k, t4)]     = (ushort_t)rx0[k];
        Xt[swzi(qq * 16 + 8 + k, t4)] = (ushort_t)rx1[k];
    }
    if (tid < 64) {
        float dt = dtb[(rowg0 + tid) * NHEADS + h];
        float A = -__expf(A_log[h]);
        float P = dt * A;
#pragma unroll
        for (int off = 1; off < 64; off <<= 1) {
            float o = __shfl_up(P, off);
            if (tid >= off) P += o;
        }
        sP[tid] = P;
        sdt[tid] = dt;
        float P63 = __shfl(P, 63);
        sWf[tid] = __expf(P63 - P) * dt;
        expPb[(size_t)(b * NHEADS + h) * L_SEQ + c * 64 + tid] = __expf(P);
    }
    __syncthreads();

    {
        const float w = sWf[t4];
#pragma unroll
        for (int k = 0; k < 8; ++k) {
            Bw[swzi(qq * 16 + k, t4)]     = f2bf(bf2f((ushort_t)rb0[k]) * w);
            Bw[swzi(qq * 16 + 8 + k, t4)] = f2bf(bf2f((ushort_t)rb1[k]) * w);
        }
    }

    // ---- MFMA 1: S = C.B^T ----
    const float Dh = Dvec[h];
    {
        short8 a0 = *(const short8*)&Cs[swzi(wv * 16 + lr, lk * 8)];
        short8 a1 = *(const short8*)&Cs[swzi(wv * 16 + lr, 32 + lk * 8)];
        f32x4 acc[4];
        const f32x4 zero = {0.f, 0.f, 0.f, 0.f};
#pragma unroll
        for (int nj = 0; nj < 4; ++nj) {
            short8 b0 = *(const short8*)&Bs[swzi(nj * 16 + lr, lk * 8)];
            short8 b1 = *(const short8*)&Bs[swzi(nj * 16 + lr, 32 + lk * 8)];
            acc[nj] = __builtin_amdgcn_mfma_f32_16x16x32_bf16(a0, b0, zero, 0, 0, 0);
            acc[nj] = __builtin_amdgcn_mfma_f32_16x16x32_bf16(a1, b1, acc[nj], 0, 0, 0);
        }
#pragma unroll
        for (int r = 0; r < 4; ++r) {
            const int i = wv * 16 + lk * 4 + r;
            const float Pi = sP[i];
#pragma unroll
            for (int nj = 0; nj < 4; ++nj) {
                const int j = nj * 16 + lr;
                float s = 0.f;
                if (j <= i) s = acc[nj][r] * __expf(Pi - sP[j]) * sdt[j];
                if (j == i) s += Dh;
                Ss[swzi(i, j)] = f2bf(s);
            }
        }
    }
    __syncthreads();

    // ---- MFMA 2: Y = S.X -> ybuf ----
    {
        short8 a0 = *(const short8*)&Ss[swzi(wv * 16 + lr, lk * 8)];
        short8 a1 = *(const short8*)&Ss[swzi(wv * 16 + lr, 32 + lk * 8)];
        const f32x4 zero = {0.f, 0.f, 0.f, 0.f};
#pragma unroll
        for (int np = 0; np < 4; ++np) {
            short8 b0 = *(const short8*)&Xt[swzi(np * 16 + lr, lk * 8)];
            short8 b1 = *(const short8*)&Xt[swzi(np * 16 + lr, 32 + lk * 8)];
            f32x4 acc = __builtin_amdgcn_mfma_f32_16x16x32_bf16(a0, b0, zero, 0, 0, 0);
            acc = __builtin_amdgcn_mfma_f32_16x16x32_bf16(a1, b1, acc, 0, 0, 0);
#pragma unroll
            for (int r = 0; r < 4; ++r) {
                const int i = wv * 16 + lk * 4 + r;
                const int p = np * 16 + lr;
                ybuf[(rowg0 + i) * DINNER + (size_t)h * 64 + p] = f2bf(acc[r]);
            }
        }
    }

    // ---- MFMA 3: G^T[p][n] = Xt . Bw^T -> Gbuf ([p][n] layout) ----
    {
        short8 a0 = *(const short8*)&Xt[swzi(wv * 16 + lr, lk * 8)];
        short8 a1 = *(const short8*)&Xt[swzi(wv * 16 + lr, 32 + lk * 8)];
        const f32x4 zero = {0.f, 0.f, 0.f, 0.f};
        const size_t gbase = ((size_t)((b * NHEADS + h) * NCHUNK + c)) << 12;
#pragma unroll
        for (int nt = 0; nt < 4; ++nt) {
            short8 b0 = *(const short8*)&Bw[swzi(nt * 16 + lr, lk * 8)];
            short8 b1 = *(const short8*)&Bw[swzi(nt * 16 + lr, 32 + lk * 8)];
            f32x4 acc = __builtin_amdgcn_mfma_f32_16x16x32_bf16(a0, b0, zero, 0, 0, 0);
            acc = __builtin_amdgcn_mfma_f32_16x16x32_bf16(a1, b1, acc, 0, 0, 0);
#pragma unroll
            for (int r = 0; r < 4; ++r) {
                const int p = wv * 16 + lk * 4 + r;
                const int n = nt * 16 + lr;
                Gbuf[gbase + p * 64 + n] = f2bf(acc[r]);
            }
        }
    }
}

// ---------------- Phase B1: elementwise chunk-state scan (in-place G -> hstates) ----------------
__global__ __launch_bounds__(256) void state_scan_kernel(
    ushort_t* __restrict__ GH, const float* __restrict__ expPb)
{
    const int half = blockIdx.x, h = blockIdx.y, b = blockIdx.z;
    const int bh = b * NHEADS + h;
    const int e0 = half * 2048 + threadIdx.x * 8;
    ushort_t* base = GH + ((size_t)bh << 17);
    const float* ep = expPb + (size_t)bh * L_SEQ;

    float hr[8];
#pragma unroll
    for (int k = 0; k < 8; ++k) hr[k] = 0.f;

    short8 g = *(const short8*)(base + e0);
    float Ec = ep[63];
    for (int c = 0; c < NCHUNK; ++c) {
        short8 gn = g; float En = 0.f;
        if (c + 1 < NCHUNK) {
            gn = *(const short8*)(base + ((size_t)(c + 1) << 12) + e0);
            En = ep[(c + 1) * 64 + 63];
        }
        short8 o;
#pragma unroll
        for (int k = 0; k < 8; ++k) o[k] = (short)f2bf(hr[k]);
        *(short8*)(base + ((size_t)c << 12) + e0) = o;
#pragma unroll
        for (int k = 0; k < 8; ++k) hr[k] = hr[k] * Ec + bf2f((ushort_t)g[k]);
        g = gn; Ec = En;
    }
}

// ---------------- Phase B2 (MFMA): y_inter[t][p] = expP[t] * sum_n C[t][n] h[n][p] ----------------
__global__ __launch_bounds__(256) void y_inter_kernel(
    const ushort_t* __restrict__ cvb, const float* __restrict__ expPb,
    const ushort_t* __restrict__ hst, ushort_t* __restrict__ ybuf)
{
    const int c = blockIdx.x + 1, h = blockIdx.y, b = blockIdx.z;
    const int tid = threadIdx.x;
    const int wv = tid >> 6, lane = tid & 63;
    const int lr = lane & 15, lk = lane >> 4;
    const int bh = b * NHEADS + h;

    __shared__ __align__(16) ushort_t Cs[4096];  // [t][n] swz
    __shared__ __align__(16) ushort_t Hp[4096];  // [p][n] swz
    __shared__ float sEp[64];

    const int t4 = tid >> 2, qq = tid & 3;
    const size_t rowg0 = (size_t)b * L_SEQ + c * 64;
    {
        const ushort_t* rp = cvb + (rowg0 + t4) * DCONVD + DINNER + DSTATE + qq * 16;
        *(short8*)&Cs[swzi(t4, qq * 16)]     = *(const short8*)rp;
        *(short8*)&Cs[swzi(t4, qq * 16 + 8)] = *(const short8*)(rp + 8);
        const ushort_t* hr = hst + (((size_t)(bh * NCHUNK + c)) << 12) + t4 * 64 + qq * 16;
        *(short8*)&Hp[swzi(t4, qq * 16)]     = *(const short8*)hr;
        *(short8*)&Hp[swzi(t4, qq * 16 + 8)] = *(const short8*)(hr + 8);
    }
    if (tid < 64) sEp[tid] = expPb[(size_t)bh * L_SEQ + c * 64 + tid];
    __syncthreads();

    short8 a0 = *(const short8*)&Cs[swzi(wv * 16 + lr, lk * 8)];
    short8 a1 = *(const short8*)&Cs[swzi(wv * 16 + lr, 32 + lk * 8)];
    const f32x4 zero = {0.f, 0.f, 0.f, 0.f};
#pragma unroll
    for (int np = 0; np < 4; ++np) {
        short8 b0 = *(const short8*)&Hp[swzi(np * 16 + lr, lk * 8)];
        short8 b1 = *(const short8*)&Hp[swzi(np * 16 + lr, 32 + lk * 8)];
        f32x4 acc = __builtin_amdgcn_mfma_f32_16x16x32_bf16(a0, b0, zero, 0, 0, 0);
        acc = __builtin_amdgcn_mfma_f32_16x16x32_bf16(a1, b1, acc, 0, 0, 0);
#pragma unroll
        for (int r = 0; r < 4; ++r) {
            const int t = wv * 16 + lk * 4 + r;
            const int p = np * 16 + lr;
            ushort_t* yp = &ybuf[(rowg0 + t) * DINNER + (size_t)h * 64 + p];
            *yp = f2bf(bf2f(*yp) + acc[r] * sEp[t]);
        }
    }
}

// ---------------- gate (y * silu(z)) + RMSNorm -> bf16 ----------------
__global__ __launch_bounds__(256) void gatenorm_kernel(const ushort_t* __restrict__ ybuf,
                                                       const ushort_t* __restrict__ zx,
                                                       const float* __restrict__ norm_w,
                                                       ushort_t* __restrict__ gbuf) {
    const int row = blockIdx.x;
    const int tid = threadIdx.x;
    short8 yv = *(const short8*)(ybuf + (size_t)row * DINNER + tid * 8);
    short8 zv = *(const short8*)(zx + (size_t)row * LDZX + tid * 8);
    float g[8];
    float ss = 0.f;
#pragma unroll
    for (int i = 0; i < 8; ++i) {
        float y = bf2f((ushort_t)yv[i]);
        float z = bf2f((ushort_t)zv[i]);
        float sz = z / (1.f + expf(-z));
        float gg = y * sz;
        g[i] = gg;
        ss += gg * gg;
    }
#pragma unroll
    for (int o = 32; o > 0; o >>= 1) ss += __shfl_xor(ss, o);
    __shared__ float wsum[4];
    if ((tid & 63) == 0) wsum[tid >> 6] = ss;
    __syncthreads();
    float tot = wsum[0] + wsum[1] + wsum[2] + wsum[3];
    float scale = rsqrtf(tot * (1.0f / (float)DINNER) + 1e-5f);
    short8 o8;
#pragma unroll
    for (int i = 0; i < 8; ++i)
        o8[i] = (short)f2bf(g[i] * scale * norm_w[tid * 8 + i]);
    *(short8*)(gbuf + (size_t)row * DINNER + tid * 8) = o8;
}

// ---------------- launch ----------------
extern "C" void kernel_launch(void* const* d_in, const int* in_sizes, int n_in,
                              void* d_out, int out_size, void* d_ws, size_t ws_size,
                              hipStream_t stream) {
    const float* x          = (const float*)d_in[0];
    const float* in_proj_w  = (const float*)d_in[1];
    const float* conv_w     = (const float*)d_in[2];
    const float* conv_b     = (const float*)d_in[3];
    const float* dt_bias    = (const float*)d_in[4];
    const float* A_log      = (const float*)d_in[5];
    const float* Dvec       = (const float*)d_in[6];
    const float* norm_w     = (const float*)d_in[7];
    const float* out_proj_w = (const float*)d_in[8];
    float* out = (float*)d_out;

    char* ws = (char*)d_ws;
    size_t off = 0;
    ushort_t* owbf  = (ushort_t*)(ws + off); off += (size_t)KDIM * DINNER * 2;     // 4.2 MB
    ushort_t* zx    = (ushort_t*)(ws + off); off += (size_t)NROWS * LDZX * 2;      // 71.3 MB
    ushort_t* cvb   = (ushort_t*)(ws + off); off += (size_t)NROWS * DCONVD * 2;    // 35.7 MB
    float*    dtb   = (float*)(ws + off);    off += (size_t)NROWS * NHEADS * 4;    // 1.05 MB
    float*    expPb = (float*)(ws + off);    off += (size_t)128 * L_SEQ * 4;       // 1.05 MB
    ushort_t* ybuf  = (ushort_t*)(ws + off); off += (size_t)NROWS * DINNER * 2;    // 33.6 MB
    char* tail = ws + off;
    ushort_t* xbf  = (ushort_t*)tail;
    ushort_t* wbf  = (ushort_t*)(tail + (size_t)NROWS * KDIM * 2);
    ushort_t* Gbuf = (ushort_t*)tail;
    ushort_t* gbuf = (ushort_t*)tail;

    // casts
    cast_bf16_kernel<<<8192, 256, 0, stream>>>(x, xbf, NROWS * KDIM / 4);
    cast_pad_w_kernel<<<4352, 256, 0, stream>>>(in_proj_w, wbf);
    cast_bf16_kernel<<<2048, 256, 0, stream>>>(out_proj_w, owbf, KDIM * DINNER / 4);

    // in-proj GEMM: zx[8192][4352] (bf16), 256x256 8-phase
    gemm256_kernel<<<544, 512, 0, stream>>>(xbf, wbf, zx);

    // conv + silu
    conv_silu_kernel<<<dim3((DCONVD + 255) / 256, NROWS), 256, 0, stream>>>(zx, conv_w, conv_b, cvb);

    // dt
    dt_kernel<<<NROWS * NHEADS / 256, 256, 0, stream>>>(zx, dt_bias, dtb);

    // chunked scan: phase A (parallel, MFMA)
    chunk_intra_kernel<<<dim3(NCHUNK, NHEADS, 4), 256, 0, stream>>>(
        cvb, dtb, A_log, Dvec, ybuf, Gbuf, expPb);
    // phase B1: elementwise state scan (in-place G -> hstates)
    state_scan_kernel<<<dim3(2, NHEADS, 4), 256, 0, stream>>>(Gbuf, expPb);
    // phase B2: inter-chunk contribution (parallel MFMA matmuls)
    y_inter_kernel<<<dim3(NCHUNK - 1, NHEADS, 4), 256, 0, stream>>>(
        cvb, expPb, Gbuf, ybuf);

    // gate + rmsnorm
    gatenorm_kernel<<<NROWS, 256, 0, stream>>>(ybuf, zx, norm_w, gbuf);

    // out-proj GEMM -> d_out (f32)
    gemm_bt_kernel<false><<<dim3(KDIM / 128, NROWS / 128), 256, 0, stream>>>(
        gbuf, owbf, out, DINNER, KDIM);
}

// Round 6
// 329.241 us; speedup vs baseline: 4.7182x; 1.0355x over previous
//
#include <hip/hip_runtime.h>
#include <stdint.h>

typedef unsigned short ushort_t;
typedef __attribute__((ext_vector_type(4))) float f32x4;
typedef __attribute__((ext_vector_type(8))) short short8;
typedef __attribute__((ext_vector_type(4))) unsigned short us4;

#define L_SEQ   2048
#define NROWS   8192          // B*L = 4*2048
#define KDIM    1024
#define DINNER  2048
#define NHEADS  32
#define DSTATE  64
#define DCONVD  2176          // D_INNER + 2*D_STATE
#define NPROJ   4256
#define NPROJP  4352          // padded to 17*256
#define LDZX    4352
#define NCHUNK  32            // L / 64

__device__ __forceinline__ float bf2f(ushort_t u) {
    union { uint32_t i; float f; } v; v.i = ((uint32_t)u) << 16; return v.f;
}
__device__ __forceinline__ ushort_t f2bf(float f) {
    uint32_t x = __float_as_uint(f);
    x += 0x7FFFu + ((x >> 16) & 1u);
    return (ushort_t)(x >> 16);
}
__device__ __forceinline__ int swzi(int row, int col) {
    return row * 64 + (col ^ ((row & 7) << 3));
}

// ---------------- cast kernels ----------------
__global__ __launch_bounds__(256) void cast_bf16_kernel(const float* __restrict__ in,
                                                        ushort_t* __restrict__ out, int n4) {
    int i = blockIdx.x * 256 + threadIdx.x;
    if (i >= n4) return;
    float4 v = ((const float4*)in)[i];
    ushort4 o;
    o.x = f2bf(v.x); o.y = f2bf(v.y); o.z = f2bf(v.z); o.w = f2bf(v.w);
    ((ushort4*)out)[i] = o;
}

__global__ __launch_bounds__(256) void cast_pad_w_kernel(const float* __restrict__ w,
                                                         ushort_t* __restrict__ out) {
    int i = blockIdx.x * 256 + threadIdx.x;   // group of 4 elems
    int idx = i * 4;
    int row = idx >> 10;
    ushort4 o;
    if (row < NPROJ) {
        float4 v = ((const float4*)w)[i];
        o.x = f2bf(v.x); o.y = f2bf(v.y); o.z = f2bf(v.z); o.w = f2bf(v.w);
    } else {
        o.x = 0; o.y = 0; o.z = 0; o.w = 0;
    }
    ((ushort4*)out)[i] = o;
}

__device__ __forceinline__ void async16(const void* g, void* l) {
    __builtin_amdgcn_global_load_lds((const __attribute__((address_space(1))) void*)g,
                                     (__attribute__((address_space(3))) void*)l, 16, 0, 0);
}

// ---------------- 256xBN 2-phase GEMM: C[M][N] = A[M][K] * B[N][K]^T ----------------
// 8 waves (2M x 4N), BK=64, double-buffered LDS, counted vmcnt(4) (never 0 mid-loop),
// T2 swizzle via inverse-swizzled global source + swizzled ds_read (rule #21).
// Per K-tile: stage h0 -> vmcnt(4) -> barrier -> {ks0: 8+FC reads, 8*FC MFMA}
//             -> stage h1 -> {ks1: same} -> barrier.   No redundant frag reads.
template<int BN, bool OUT_BF16>
__global__ __launch_bounds__(512, 1) void gemm256_kernel(const ushort_t* __restrict__ Ap,
                                                         const ushort_t* __restrict__ Bp,
                                                         void* __restrict__ Cp,
                                                         const int K, const int ldc,
                                                         const int ntn) {
    constexpr int NBH = BN / 128;      // B half-tiles (1 or 2)
    constexpr int FC  = BN / 64;       // per-wave col frags (2 or 4)
    __shared__ ushort_t ldsA[2][2][8192];
    __shared__ ushort_t ldsB[2][NBH][8192];

    const int tid = threadIdx.x;
    const int w = tid >> 6, l = tid & 63;
    const int lr = l & 15, lk = l >> 4;
    const int wm = w >> 2, wn = w & 3;

    // XCD-bijective block swizzle (gridDim.x % 8 == 0 in both uses)
    const int lin = blockIdx.x;
    const int cpx = gridDim.x >> 3;
    const int swz = (lin & 7) * cpx + (lin >> 3);
    const int nt = swz % ntn, mt = swz / ntn;
    const int m0 = mt * 256, n0 = nt * BN;

    // staging: slot s = {tid, 512+tid} -> LDS row s>>3, 16B-slot s&7;
    // global source column (s&7) ^ (row&7)  (inverse of the read swizzle)
    const int row0 = tid >> 3,          c0 = (tid & 7) ^ (row0 & 7);
    const int row1 = (512 + tid) >> 3,  c1 = ((512 + tid) & 7) ^ (row1 & 7);

    const int bcol = wn * (BN / 4);
    const int bh = bcol >> 7, bw0 = bcol & 127;

    f32x4 acc[8][FC];
    const f32x4 zero = {0.f, 0.f, 0.f, 0.f};
#pragma unroll
    for (int i = 0; i < 8; ++i)
#pragma unroll
        for (int j = 0; j < FC; ++j) acc[i][j] = zero;

    auto stage = [&](int d_, int isB, int h_, int ktn) {
        const ushort_t* gb = (isB ? Bp + (size_t)(n0 + h_ * 128) * K
                                  : Ap + (size_t)(m0 + h_ * 128) * K) + (size_t)ktn * 64;
        ushort_t* lb = isB ? &ldsB[d_][h_][0] : &ldsA[d_][h_][0];
        async16(gb + (size_t)row0 * K + c0 * 8, lb + w * 512);
        async16(gb + (size_t)row1 * K + c1 * 8, lb + 4096 + w * 512);
    };

#define COMPUTE_KS(ks_) do {                                                          \
        short8 af[8], bfv[FC];                                                        \
        _Pragma("unroll")                                                             \
        for (int fr = 0; fr < 8; ++fr) {                                              \
            const int ar = fr * 16 + lr;                                              \
            af[fr] = *(const short8*)&Ah[ar * 64 + ((((ks_) * 4 + lk) ^ (ar & 7)) << 3)]; \
        }                                                                             \
        _Pragma("unroll")                                                             \
        for (int fc = 0; fc < FC; ++fc) {                                             \
            const int br = bw0 + fc * 16 + lr;                                        \
            bfv[fc] = *(const short8*)&Bh[br * 64 + ((((ks_) * 4 + lk) ^ (br & 7)) << 3)]; \
        }                                                                             \
        __builtin_amdgcn_s_setprio(1);                                                \
        _Pragma("unroll")                                                             \
        for (int fr = 0; fr < 8; ++fr)                                                \
            _Pragma("unroll")                                                         \
            for (int fc = 0; fc < FC; ++fc)                                           \
                acc[fr][fc] = __builtin_amdgcn_mfma_f32_16x16x32_bf16(                \
                    af[fr], bfv[fc], acc[fr][fc], 0, 0, 0);                           \
        __builtin_amdgcn_s_setprio(0);                                                \
    } while (0)

    // prologue: stage kt=0 fully into dbuf 0
    stage(0, 0, 0, 0); stage(0, 1, 0, 0);
    stage(0, 0, 1, 0);
    if (NBH == 2) stage(0, 1, 1, 0);

    const int NKT = K >> 6;
    for (int kt = 0; kt < NKT; ++kt) {
        const int d = kt & 1;
        const bool more = (kt + 1 < NKT);
        const ushort_t* Ah = &ldsA[d][wm][0];
        const ushort_t* Bh = &ldsB[d][bh][0];

        // phase 0: issue next-tile first halves, then wait current tile landed
        if (more) { stage(d ^ 1, 0, 0, kt + 1); stage(d ^ 1, 1, 0, kt + 1); }
        if (more) asm volatile("s_waitcnt vmcnt(4)" ::: "memory");
        else      asm volatile("s_waitcnt vmcnt(0)" ::: "memory");
        __builtin_amdgcn_s_barrier();

        COMPUTE_KS(0);

        // phase 1: issue next-tile second halves (overlaps ks0 MFMA / ks1 reads)
        if (more) { stage(d ^ 1, 0, 1, kt + 1); if (NBH == 2) stage(d ^ 1, 1, 1, kt + 1); }

        COMPUTE_KS(1);

        __builtin_amdgcn_s_barrier();   // all reads of buf d done before it is re-staged
    }
#undef COMPUTE_KS

    // epilogue
#pragma unroll
    for (int fr2 = 0; fr2 < 8; ++fr2)
#pragma unroll
        for (int fc2 = 0; fc2 < FC; ++fc2) {
            const int col = n0 + bcol + fc2 * 16 + lr;
            const int rowb = m0 + wm * 128 + fr2 * 16 + lk * 4;
#pragma unroll
            for (int r = 0; r < 4; ++r) {
                if (OUT_BF16)
                    ((ushort_t*)Cp)[(size_t)(rowb + r) * ldc + col] = f2bf(acc[fr2][fc2][r]);
                else
                    ((float*)Cp)[(size_t)(rowb + r) * ldc + col] = acc[fr2][fc2][r];
            }
        }
}

// ---------------- conv (4-tap causal) + SiLU, short8-vectorized ----------------
__global__ __launch_bounds__(256) void conv_silu_kernel(const ushort_t* __restrict__ zx,
                                                        const float* __restrict__ conv_w,
                                                        const float* __restrict__ conv_b,
                                                        ushort_t* __restrict__ convout) {
    const int idx = blockIdx.x * 256 + threadIdx.x;   // NROWS * 272
    const int row = idx / 272;
    const int c = (idx - row * 272) * 8;
    const int l = row & (L_SEQ - 1);
    float acc[8];
    {
        const float4* bp = (const float4*)(conv_b + c);
        float4 b0 = bp[0], b1 = bp[1];
        acc[0] = b0.x; acc[1] = b0.y; acc[2] = b0.z; acc[3] = b0.w;
        acc[4] = b1.x; acc[5] = b1.y; acc[6] = b1.z; acc[7] = b1.w;
    }
    float wv[8][4];
    {
        const float4* wp = (const float4*)(conv_w + c * 4);
#pragma unroll
        for (int i = 0; i < 8; ++i) {
            float4 t = wp[i];
            wv[i][0] = t.x; wv[i][1] = t.y; wv[i][2] = t.z; wv[i][3] = t.w;
        }
    }
#pragma unroll
    for (int k = 0; k < 4; ++k) {
        const int ll = l - 3 + k;
        if (ll >= 0) {
            short8 v = *(const short8*)(zx + (size_t)(row - 3 + k) * LDZX + DINNER + c);
#pragma unroll
            for (int i = 0; i < 8; ++i)
                acc[i] += bf2f((ushort_t)v[i]) * wv[i][k];
        }
    }
    short8 o;
#pragma unroll
    for (int i = 0; i < 8; ++i) {
        float s = acc[i] / (1.f + expf(-acc[i]));
        o[i] = (short)f2bf(s);
    }
    *(short8*)(convout + (size_t)row * DCONVD + c) = o;
}

// ---------------- dt = softplus(raw + bias) ----------------
__global__ __launch_bounds__(256) void dt_kernel(const ushort_t* __restrict__ zx,
                                                 const float* __restrict__ dt_bias,
                                                 float* __restrict__ dtb) {
    int idx = blockIdx.x * 256 + threadIdx.x;   // NROWS*32
    int row = idx >> 5;
    int h = idx & 31;
    float v = bf2f(zx[(size_t)row * LDZX + NPROJ - NHEADS + h]) + dt_bias[h];
    dtb[idx] = (v > 20.f) ? v : log1pf(expf(v));
}

// ---------------- Phase A (MFMA): per-chunk intra output + chunk state G ----------------
__global__ __launch_bounds__(256) void chunk_intra_kernel(
    const ushort_t* __restrict__ cvb, const float* __restrict__ dtb,
    const float* __restrict__ A_log, const float* __restrict__ Dvec,
    ushort_t* __restrict__ ybuf, ushort_t* __restrict__ Gbuf,
    float* __restrict__ expPb)
{
    const int c = blockIdx.x, h = blockIdx.y, b = blockIdx.z;
    const int tid = threadIdx.x;
    const int wv = tid >> 6, lane = tid & 63;
    const int lr = lane & 15, lk = lane >> 4;

    __shared__ __align__(16) ushort_t Cs[4096];  // [t][n] swz
    __shared__ __align__(16) ushort_t Bs[4096];  // [t][n] swz
    __shared__ __align__(16) ushort_t Xt[4096];  // [p][t] swz
    __shared__ __align__(16) ushort_t Ss[4096];  // [i][j] swz (masked S, bf16)
    __shared__ __align__(16) ushort_t Bw[4096];  // [n][t] swz (B^T * w_t)
    __shared__ float sP[64], sdt[64], sWf[64];

    const int t4 = tid >> 2, qq = tid & 3;
    const size_t rowg0 = (size_t)b * L_SEQ + c * 64;
    const ushort_t* rowp = cvb + (rowg0 + t4) * DCONVD;

    short8 rb0 = *(const short8*)(rowp + DINNER + qq * 16);
    short8 rb1 = *(const short8*)(rowp + DINNER + qq * 16 + 8);
    short8 rc0 = *(const short8*)(rowp + DINNER + DSTATE + qq * 16);
    short8 rc1 = *(const short8*)(rowp + DINNER + DSTATE + qq * 16 + 8);
    short8 rx0 = *(const short8*)(rowp + h * 64 + qq * 16);
    short8 rx1 = *(const short8*)(rowp + h * 64 + qq * 16 + 8);

    *(short8*)&Cs[swzi(t4, qq * 16)]     = rc0;
    *(short8*)&Cs[swzi(t4, qq * 16 + 8)] = rc1;
    *(short8*)&Bs[swzi(t4, qq * 16)]     = rb0;
    *(short8*)&Bs[swzi(t4, qq * 16 + 8)] = rb1;
#pragma unroll
    for (int k = 0; k < 8; ++k) {
        Xt[swzi(qq * 16 + k, t4)]     = (ushort_t)rx0[k];
        Xt[swzi(qq * 16 + 8 + k, t4)] = (ushort_t)rx1[k];
    }
    if (tid < 64) {
        float dt = dtb[(rowg0 + tid) * NHEADS + h];
        float A = -__expf(A_log[h]);
        float P = dt * A;
#pragma unroll
        for (int off = 1; off < 64; off <<= 1) {
            float o = __shfl_up(P, off);
            if (tid >= off) P += o;
        }
        sP[tid] = P;
        sdt[tid] = dt;
        float P63 = __shfl(P, 63);
        sWf[tid] = __expf(P63 - P) * dt;
        expPb[(size_t)(b * NHEADS + h) * L_SEQ + c * 64 + tid] = __expf(P);
    }
    __syncthreads();

    {
        const float w = sWf[t4];
#pragma unroll
        for (int k = 0; k < 8; ++k) {
            Bw[swzi(qq * 16 + k, t4)]     = f2bf(bf2f((ushort_t)rb0[k]) * w);
            Bw[swzi(qq * 16 + 8 + k, t4)] = f2bf(bf2f((ushort_t)rb1[k]) * w);
        }
    }

    // ---- MFMA 1: S = C.B^T ----
    const float Dh = Dvec[h];
    {
        short8 a0 = *(const short8*)&Cs[swzi(wv * 16 + lr, lk * 8)];
        short8 a1 = *(const short8*)&Cs[swzi(wv * 16 + lr, 32 + lk * 8)];
        f32x4 acc[4];
        const f32x4 zero = {0.f, 0.f, 0.f, 0.f};
#pragma unroll
        for (int nj = 0; nj < 4; ++nj) {
            short8 b0 = *(const short8*)&Bs[swzi(nj * 16 + lr, lk * 8)];
            short8 b1 = *(const short8*)&Bs[swzi(nj * 16 + lr, 32 + lk * 8)];
            acc[nj] = __builtin_amdgcn_mfma_f32_16x16x32_bf16(a0, b0, zero, 0, 0, 0);
            acc[nj] = __builtin_amdgcn_mfma_f32_16x16x32_bf16(a1, b1, acc[nj], 0, 0, 0);
        }
#pragma unroll
        for (int r = 0; r < 4; ++r) {
            const int i = wv * 16 + lk * 4 + r;
            const float Pi = sP[i];
#pragma unroll
            for (int nj = 0; nj < 4; ++nj) {
                const int j = nj * 16 + lr;
                float s = 0.f;
                if (j <= i) s = acc[nj][r] * __expf(Pi - sP[j]) * sdt[j];
                if (j == i) s += Dh;
                Ss[swzi(i, j)] = f2bf(s);
            }
        }
    }
    __syncthreads();

    // ---- MFMA 2: Y = S.X -> ybuf ----
    {
        short8 a0 = *(const short8*)&Ss[swzi(wv * 16 + lr, lk * 8)];
        short8 a1 = *(const short8*)&Ss[swzi(wv * 16 + lr, 32 + lk * 8)];
        const f32x4 zero = {0.f, 0.f, 0.f, 0.f};
#pragma unroll
        for (int np = 0; np < 4; ++np) {
            short8 b0 = *(const short8*)&Xt[swzi(np * 16 + lr, lk * 8)];
            short8 b1 = *(const short8*)&Xt[swzi(np * 16 + lr, 32 + lk * 8)];
            f32x4 acc = __builtin_amdgcn_mfma_f32_16x16x32_bf16(a0, b0, zero, 0, 0, 0);
            acc = __builtin_amdgcn_mfma_f32_16x16x32_bf16(a1, b1, acc, 0, 0, 0);
#pragma unroll
            for (int r = 0; r < 4; ++r) {
                const int i = wv * 16 + lk * 4 + r;
                const int p = np * 16 + lr;
                ybuf[(rowg0 + i) * DINNER + (size_t)h * 64 + p] = f2bf(acc[r]);
            }
        }
    }

    // ---- MFMA 3: G^T[p][n] = Xt . Bw^T -> Gbuf ([p][n] layout) ----
    {
        short8 a0 = *(const short8*)&Xt[swzi(wv * 16 + lr, lk * 8)];
        short8 a1 = *(const short8*)&Xt[swzi(wv * 16 + lr, 32 + lk * 8)];
        const f32x4 zero = {0.f, 0.f, 0.f, 0.f};
        const size_t gbase = ((size_t)((b * NHEADS + h) * NCHUNK + c)) << 12;
#pragma unroll
        for (int nt = 0; nt < 4; ++nt) {
            short8 b0 = *(const short8*)&Bw[swzi(nt * 16 + lr, lk * 8)];
            short8 b1 = *(const short8*)&Bw[swzi(nt * 16 + lr, 32 + lk * 8)];
            f32x4 acc = __builtin_amdgcn_mfma_f32_16x16x32_bf16(a0, b0, zero, 0, 0, 0);
            acc = __builtin_amdgcn_mfma_f32_16x16x32_bf16(a1, b1, acc, 0, 0, 0);
#pragma unroll
            for (int r = 0; r < 4; ++r) {
                const int p = wv * 16 + lk * 4 + r;
                const int n = nt * 16 + lr;
                Gbuf[gbase + p * 64 + n] = f2bf(acc[r]);
            }
        }
    }
}

// ---------------- Phase B1: elementwise chunk-state scan (in-place G -> hstates) ----------------
__global__ __launch_bounds__(256) void state_scan_kernel(
    ushort_t* __restrict__ GH, const float* __restrict__ expPb)
{
    const int half = blockIdx.x, h = blockIdx.y, b = blockIdx.z;
    const int bh = b * NHEADS + h;
    const int e0 = half * 2048 + threadIdx.x * 8;
    ushort_t* base = GH + ((size_t)bh << 17);
    const float* ep = expPb + (size_t)bh * L_SEQ;

    float hr[8];
#pragma unroll
    for (int k = 0; k < 8; ++k) hr[k] = 0.f;

    short8 g = *(const short8*)(base + e0);
    float Ec = ep[63];
    for (int c = 0; c < NCHUNK; ++c) {
        short8 gn = g; float En = 0.f;
        if (c + 1 < NCHUNK) {
            gn = *(const short8*)(base + ((size_t)(c + 1) << 12) + e0);
            En = ep[(c + 1) * 64 + 63];
        }
        short8 o;
#pragma unroll
        for (int k = 0; k < 8; ++k) o[k] = (short)f2bf(hr[k]);
        *(short8*)(base + ((size_t)c << 12) + e0) = o;
#pragma unroll
        for (int k = 0; k < 8; ++k) hr[k] = hr[k] * Ec + bf2f((ushort_t)g[k]);
        g = gn; Ec = En;
    }
}

// ---------------- Phase B2 (MFMA): y_inter[t][p] = expP[t] * sum_n C[t][n] h[n][p] ----------------
__global__ __launch_bounds__(256) void y_inter_kernel(
    const ushort_t* __restrict__ cvb, const float* __restrict__ expPb,
    const ushort_t* __restrict__ hst, ushort_t* __restrict__ ybuf)
{
    const int c = blockIdx.x + 1, h = blockIdx.y, b = blockIdx.z;
    const int tid = threadIdx.x;
    const int wv = tid >> 6, lane = tid & 63;
    const int lr = lane & 15, lk = lane >> 4;
    const int bh = b * NHEADS + h;

    __shared__ __align__(16) ushort_t Cs[4096];  // [t][n] swz
    __shared__ __align__(16) ushort_t Hp[4096];  // [p][n] swz
    __shared__ float sEp[64];

    const int t4 = tid >> 2, qq = tid & 3;
    const size_t rowg0 = (size_t)b * L_SEQ + c * 64;
    {
        const ushort_t* rp = cvb + (rowg0 + t4) * DCONVD + DINNER + DSTATE + qq * 16;
        *(short8*)&Cs[swzi(t4, qq * 16)]     = *(const short8*)rp;
        *(short8*)&Cs[swzi(t4, qq * 16 + 8)] = *(const short8*)(rp + 8);
        const ushort_t* hr = hst + (((size_t)(bh * NCHUNK + c)) << 12) + t4 * 64 + qq * 16;
        *(short8*)&Hp[swzi(t4, qq * 16)]     = *(const short8*)hr;
        *(short8*)&Hp[swzi(t4, qq * 16 + 8)] = *(const short8*)(hr + 8);
    }
    if (tid < 64) sEp[tid] = expPb[(size_t)bh * L_SEQ + c * 64 + tid];
    __syncthreads();

    short8 a0 = *(const short8*)&Cs[swzi(wv * 16 + lr, lk * 8)];
    short8 a1 = *(const short8*)&Cs[swzi(wv * 16 + lr, 32 + lk * 8)];
    const f32x4 zero = {0.f, 0.f, 0.f, 0.f};
#pragma unroll
    for (int np = 0; np < 4; ++np) {
        short8 b0 = *(const short8*)&Hp[swzi(np * 16 + lr, lk * 8)];
        short8 b1 = *(const short8*)&Hp[swzi(np * 16 + lr, 32 + lk * 8)];
        f32x4 acc = __builtin_amdgcn_mfma_f32_16x16x32_bf16(a0, b0, zero, 0, 0, 0);
        acc = __builtin_amdgcn_mfma_f32_16x16x32_bf16(a1, b1, acc, 0, 0, 0);
#pragma unroll
        for (int r = 0; r < 4; ++r) {
            const int t = wv * 16 + lk * 4 + r;
            const int p = np * 16 + lr;
            ushort_t* yp = &ybuf[(rowg0 + t) * DINNER + (size_t)h * 64 + p];
            *yp = f2bf(bf2f(*yp) + acc[r] * sEp[t]);
        }
    }
}

// ---------------- gate (y * silu(z)) + RMSNorm -> bf16 ----------------
__global__ __launch_bounds__(256) void gatenorm_kernel(const ushort_t* __restrict__ ybuf,
                                                       const ushort_t* __restrict__ zx,
                                                       const float* __restrict__ norm_w,
                                                       ushort_t* __restrict__ gbuf) {
    const int row = blockIdx.x;
    const int tid = threadIdx.x;
    short8 yv = *(const short8*)(ybuf + (size_t)row * DINNER + tid * 8);
    short8 zv = *(const short8*)(zx + (size_t)row * LDZX + tid * 8);
    float g[8];
    float ss = 0.f;
#pragma unroll
    for (int i = 0; i < 8; ++i) {
        float y = bf2f((ushort_t)yv[i]);
        float z = bf2f((ushort_t)zv[i]);
        float sz = z / (1.f + expf(-z));
        float gg = y * sz;
        g[i] = gg;
        ss += gg * gg;
    }
#pragma unroll
    for (int o = 32; o > 0; o >>= 1) ss += __shfl_xor(ss, o);
    __shared__ float wsum[4];
    if ((tid & 63) == 0) wsum[tid >> 6] = ss;
    __syncthreads();
    float tot = wsum[0] + wsum[1] + wsum[2] + wsum[3];
    float scale = rsqrtf(tot * (1.0f / (float)DINNER) + 1e-5f);
    short8 o8;
#pragma unroll
    for (int i = 0; i < 8; ++i)
        o8[i] = (short)f2bf(g[i] * scale * norm_w[tid * 8 + i]);
    *(short8*)(gbuf + (size_t)row * DINNER + tid * 8) = o8;
}

// ---------------- launch ----------------
extern "C" void kernel_launch(void* const* d_in, const int* in_sizes, int n_in,
                              void* d_out, int out_size, void* d_ws, size_t ws_size,
                              hipStream_t stream) {
    const float* x          = (const float*)d_in[0];
    const float* in_proj_w  = (const float*)d_in[1];
    const float* conv_w     = (const float*)d_in[2];
    const float* conv_b     = (const float*)d_in[3];
    const float* dt_bias    = (const float*)d_in[4];
    const float* A_log      = (const float*)d_in[5];
    const float* Dvec       = (const float*)d_in[6];
    const float* norm_w     = (const float*)d_in[7];
    const float* out_proj_w = (const float*)d_in[8];
    float* out = (float*)d_out;

    char* ws = (char*)d_ws;
    size_t off = 0;
    ushort_t* owbf  = (ushort_t*)(ws + off); off += (size_t)KDIM * DINNER * 2;     // 4.2 MB
    ushort_t* zx    = (ushort_t*)(ws + off); off += (size_t)NROWS * LDZX * 2;      // 71.3 MB
    ushort_t* cvb   = (ushort_t*)(ws + off); off += (size_t)NROWS * DCONVD * 2;    // 35.7 MB
    float*    dtb   = (float*)(ws + off);    off += (size_t)NROWS * NHEADS * 4;    // 1.05 MB
    float*    expPb = (float*)(ws + off);    off += (size_t)128 * L_SEQ * 4;       // 1.05 MB
    ushort_t* ybuf  = (ushort_t*)(ws + off); off += (size_t)NROWS * DINNER * 2;    // 33.6 MB
    char* tail = ws + off;
    ushort_t* xbf  = (ushort_t*)tail;
    ushort_t* wbf  = (ushort_t*)(tail + (size_t)NROWS * KDIM * 2);
    ushort_t* Gbuf = (ushort_t*)tail;
    ushort_t* gbuf = (ushort_t*)tail;

    // casts
    cast_bf16_kernel<<<8192, 256, 0, stream>>>(x, xbf, NROWS * KDIM / 4);
    cast_pad_w_kernel<<<4352, 256, 0, stream>>>(in_proj_w, wbf);
    cast_bf16_kernel<<<2048, 256, 0, stream>>>(out_proj_w, owbf, KDIM * DINNER / 4);

    // in-proj GEMM: zx[8192][4352] (bf16), 256x256 2-phase  (grid 544 = 8*68)
    gemm256_kernel<256, true><<<544, 512, 0, stream>>>(xbf, wbf, zx, KDIM, LDZX, 17);

    // conv + silu (short8-vectorized)
    conv_silu_kernel<<<NROWS * 272 / 256, 256, 0, stream>>>(zx, conv_w, conv_b, cvb);

    // dt
    dt_kernel<<<NROWS * NHEADS / 256, 256, 0, stream>>>(zx, dt_bias, dtb);

    // chunked scan: phase A (parallel, MFMA)
    chunk_intra_kernel<<<dim3(NCHUNK, NHEADS, 4), 256, 0, stream>>>(
        cvb, dtb, A_log, Dvec, ybuf, Gbuf, expPb);
    // phase B1: elementwise state scan (in-place G -> hstates)
    state_scan_kernel<<<dim3(2, NHEADS, 4), 256, 0, stream>>>(Gbuf, expPb);
    // phase B2: inter-chunk contribution (parallel MFMA matmuls)
    y_inter_kernel<<<dim3(NCHUNK - 1, NHEADS, 4), 256, 0, stream>>>(
        cvb, expPb, Gbuf, ybuf);

    // gate + rmsnorm
    gatenorm_kernel<<<NROWS, 256, 0, stream>>>(ybuf, zx, norm_w, gbuf);

    // out-proj GEMM -> d_out (f32), 256x128 2-phase  (grid 256 = 8*32, 1 round)
    gemm256_kernel<128, false><<<256, 512, 0, stream>>>(gbuf, owbf, out, DINNER, KDIM, 8);
}

// Round 7
// 325.718 us; speedup vs baseline: 4.7692x; 1.0108x over previous
//
#include <hip/hip_runtime.h>
#include <stdint.h>

typedef unsigned short ushort_t;
typedef __attribute__((ext_vector_type(4))) float f32x4;
typedef __attribute__((ext_vector_type(8))) short short8;
typedef __attribute__((ext_vector_type(4))) unsigned short us4;

#define L_SEQ   2048
#define NROWS   8192          // B*L = 4*2048
#define KDIM    1024
#define DINNER  2048
#define NHEADS  32
#define DSTATE  64
#define DCONVD  2176          // D_INNER + 2*D_STATE
#define NPROJ   4256
#define NPROJP  4352          // padded to 17*256
#define LDZX    4352
#define NCHUNK  32            // L / 64

__device__ __forceinline__ float bf2f(ushort_t u) {
    union { uint32_t i; float f; } v; v.i = ((uint32_t)u) << 16; return v.f;
}
__device__ __forceinline__ ushort_t f2bf(float f) {
    uint32_t x = __float_as_uint(f);
    x += 0x7FFFu + ((x >> 16) & 1u);
    return (ushort_t)(x >> 16);
}
__device__ __forceinline__ int swzi(int row, int col) {
    return row * 64 + (col ^ ((row & 7) << 3));
}

// ---------------- cast kernels ----------------
__global__ __launch_bounds__(256) void cast_bf16_kernel(const float* __restrict__ in,
                                                        ushort_t* __restrict__ out, int n4) {
    int i = blockIdx.x * 256 + threadIdx.x;
    if (i >= n4) return;
    float4 v = ((const float4*)in)[i];
    ushort4 o;
    o.x = f2bf(v.x); o.y = f2bf(v.y); o.z = f2bf(v.z); o.w = f2bf(v.w);
    ((ushort4*)out)[i] = o;
}

__global__ __launch_bounds__(256) void cast_pad_w_kernel(const float* __restrict__ w,
                                                         ushort_t* __restrict__ out) {
    int i = blockIdx.x * 256 + threadIdx.x;   // group of 4 elems
    int idx = i * 4;
    int row = idx >> 10;
    ushort4 o;
    if (row < NPROJ) {
        float4 v = ((const float4*)w)[i];
        o.x = f2bf(v.x); o.y = f2bf(v.y); o.z = f2bf(v.z); o.w = f2bf(v.w);
    } else {
        o.x = 0; o.y = 0; o.z = 0; o.w = 0;
    }
    ((ushort4*)out)[i] = o;
}

__device__ __forceinline__ void async16(const void* g, void* l) {
    __builtin_amdgcn_global_load_lds((const __attribute__((address_space(1))) void*)g,
                                     (__attribute__((address_space(3))) void*)l, 16, 0, 0);
}

// ---------------- 256xBN 4-phase pipelined GEMM: C[M][N] = A[M][K] * B[N][K]^T --------
// 8 waves (2M x 4N), BK=64 split into two K-halves of 32. LDS half-tile = full panel
// rows x 32K, so every phase needs only its own K-half (uniform across waves) ->
// counted vmcnt works without draining.  Per K-tile:
//   p0(ks0,fr0-3): reads -> stage A.k0[t+1] -> bar -> 16*FC/4 MFMA -> bar
//   p1(ks0,fr4-7): reads -> stage B.k0[t+1] -> bar -> MFMA -> vmcnt(VN) -> bar   (k1[t] confirmed)
//   p2(ks1,fr0-3): reads -> stage A.k1[t+1] -> bar -> MFMA -> bar
//   p3(ks1,fr4-7): reads -> stage B.k1[t+1] -> bar -> MFMA -> vmcnt(VN) -> bar   (k0[t+1] confirmed)
// Swizzle: LDS slot = lk ^ (row&3) ^ ((row>>2)&3), inverse-applied on global source.
template<int BN, bool OUT_BF16>
__global__ __launch_bounds__(512, 1) void gemm256_kernel(const ushort_t* __restrict__ Ap,
                                                         const ushort_t* __restrict__ Bp,
                                                         void* __restrict__ Cp,
                                                         const int K, const int ldc,
                                                         const int ntn) {
    constexpr int FC = BN / 64;        // per-wave col frags (4 or 2)
    constexpr int LB = BN / 128;       // per-wave loads per B K-half (2 or 1)
    constexpr int VN = 2 + LB;         // counted vmcnt value (4 or 3)
    __shared__ ushort_t ldsA[2][2][256 * 32];   // [buf][khalf][row*32]
    __shared__ ushort_t ldsB[2][2][BN * 32];

    const int tid = threadIdx.x;
    const int w = tid >> 6, l = tid & 63;
    const int lr = l & 15, lk = l >> 4;
    const int wm = w >> 2, wn = w & 3;

    // XCD-bijective block swizzle (gridDim.x % 8 == 0 in both uses)
    const int lin = blockIdx.x;
    const int cpx = gridDim.x >> 3;
    const int swz = (lin & 7) * cpx + (lin >> 3);
    const int nt = swz % ntn, mt = swz / ntn;
    const int m0 = mt * 256, n0 = nt * BN;
    const int bcol = wn * (BN / 4);

    // staging slot constants: slot s -> row s>>2, 16B-slot s&3;
    // global k-chunk g = (s&3) ^ (row&3) ^ ((row>>2)&3)  (inverse of read swizzle)
    const int sr0 = tid >> 2,         sg0 = (tid & 3) ^ (sr0 & 3) ^ ((sr0 >> 2) & 3);
    const int sr1 = (512 + tid) >> 2, sg1 = ((512 + tid) & 3) ^ (sr1 & 3) ^ ((sr1 >> 2) & 3);

    f32x4 acc[8][FC];
    const f32x4 zero = {0.f, 0.f, 0.f, 0.f};
#pragma unroll
    for (int i = 0; i < 8; ++i)
#pragma unroll
        for (int j = 0; j < FC; ++j) acc[i][j] = zero;

    auto stageA = [&](int d_, int kh, int ktn) {
        const ushort_t* gb = Ap + (size_t)m0 * K + (size_t)ktn * 64 + kh * 32;
        async16(gb + (size_t)sr0 * K + sg0 * 8, (ushort_t*)&ldsA[d_][kh][0] + tid * 8);
        async16(gb + (size_t)sr1 * K + sg1 * 8, (ushort_t*)&ldsA[d_][kh][0] + (512 + tid) * 8);
    };
    auto stageB = [&](int d_, int kh, int ktn) {
        const ushort_t* gb = Bp + (size_t)n0 * K + (size_t)ktn * 64 + kh * 32;
        async16(gb + (size_t)sr0 * K + sg0 * 8, (ushort_t*)&ldsB[d_][kh][0] + tid * 8);
        if constexpr (LB == 2)
            async16(gb + (size_t)sr1 * K + sg1 * 8, (ushort_t*)&ldsB[d_][kh][0] + (512 + tid) * 8);
    };

#define VMWAIT_VN do { if constexpr (VN == 4) asm volatile("s_waitcnt vmcnt(4)" ::: "memory"); \
                       else                   asm volatile("s_waitcnt vmcnt(3)" ::: "memory"); } while (0)
#define VMWAIT_0  asm volatile("s_waitcnt vmcnt(0)" ::: "memory")

    short8 bfv[FC];

#define PHASE(ks_, frh_, STAGE_STMT, VM_STMT) do {                                      \
        short8 af[4];                                                                   \
        _Pragma("unroll")                                                               \
        for (int fr = 0; fr < 4; ++fr) {                                                \
            const int row = wm * 128 + ((frh_) * 4 + fr) * 16 + lr;                     \
            const int sl = lk ^ (row & 3) ^ ((row >> 2) & 3);                           \
            af[fr] = *(const short8*)&ldsA[d][ks_][row * 32 + sl * 8];                  \
        }                                                                               \
        if ((frh_) == 0) {                                                              \
            _Pragma("unroll")                                                           \
            for (int fc = 0; fc < FC; ++fc) {                                           \
                const int row = bcol + fc * 16 + lr;                                    \
                const int sl = lk ^ (row & 3) ^ ((row >> 2) & 3);                       \
                bfv[fc] = *(const short8*)&ldsB[d][ks_][row * 32 + sl * 8];             \
            }                                                                           \
        }                                                                               \
        STAGE_STMT;                                                                     \
        __builtin_amdgcn_s_barrier();                                                   \
        __builtin_amdgcn_s_setprio(1);                                                  \
        _Pragma("unroll")                                                               \
        for (int fr = 0; fr < 4; ++fr)                                                  \
            _Pragma("unroll")                                                           \
            for (int fc = 0; fc < FC; ++fc)                                             \
                acc[(frh_) * 4 + fr][fc] = __builtin_amdgcn_mfma_f32_16x16x32_bf16(     \
                    af[fr], bfv[fc], acc[(frh_) * 4 + fr][fc], 0, 0, 0);                \
        __builtin_amdgcn_s_setprio(0);                                                  \
        VM_STMT;                                                                        \
        __builtin_amdgcn_s_barrier();                                                   \
    } while (0)

    // prologue: stage tile 0 (A.k0, B.k0, A.k1, B.k1), confirm k0 halves
    stageA(0, 0, 0); stageB(0, 0, 0);
    stageA(0, 1, 0); stageB(0, 1, 0);
    VMWAIT_VN;
    __builtin_amdgcn_s_barrier();

    const int NKT = K >> 6;
    for (int kt = 0; kt < NKT; ++kt) {
        const int d = kt & 1;
        const bool more = (kt + 1 < NKT);
        PHASE(0, 0, { if (more) stageA(d ^ 1, 0, kt + 1); }, {});
        PHASE(0, 1, { if (more) stageB(d ^ 1, 0, kt + 1); },
                    { if (more) VMWAIT_VN; else VMWAIT_0; });
        PHASE(1, 0, { if (more) stageA(d ^ 1, 1, kt + 1); }, {});
        PHASE(1, 1, { if (more) stageB(d ^ 1, 1, kt + 1); },
                    { if (more) VMWAIT_VN; });
    }
#undef PHASE
#undef VMWAIT_VN
#undef VMWAIT_0

    // epilogue
#pragma unroll
    for (int fr2 = 0; fr2 < 8; ++fr2)
#pragma unroll
        for (int fc2 = 0; fc2 < FC; ++fc2) {
            const int col = n0 + bcol + fc2 * 16 + lr;
            const int rowb = m0 + wm * 128 + fr2 * 16 + lk * 4;
#pragma unroll
            for (int r = 0; r < 4; ++r) {
                if (OUT_BF16)
                    ((ushort_t*)Cp)[(size_t)(rowb + r) * ldc + col] = f2bf(acc[fr2][fc2][r]);
                else
                    ((float*)Cp)[(size_t)(rowb + r) * ldc + col] = acc[fr2][fc2][r];
            }
        }
}

// ---------------- conv (4-tap causal) + SiLU, short8-vectorized ----------------
__global__ __launch_bounds__(256) void conv_silu_kernel(const ushort_t* __restrict__ zx,
                                                        const float* __restrict__ conv_w,
                                                        const float* __restrict__ conv_b,
                                                        ushort_t* __restrict__ convout) {
    const int idx = blockIdx.x * 256 + threadIdx.x;   // NROWS * 272
    const int row = idx / 272;
    const int c = (idx - row * 272) * 8;
    const int l = row & (L_SEQ - 1);
    float acc[8];
    {
        const float4* bp = (const float4*)(conv_b + c);
        float4 b0 = bp[0], b1 = bp[1];
        acc[0] = b0.x; acc[1] = b0.y; acc[2] = b0.z; acc[3] = b0.w;
        acc[4] = b1.x; acc[5] = b1.y; acc[6] = b1.z; acc[7] = b1.w;
    }
    float wv[8][4];
    {
        const float4* wp = (const float4*)(conv_w + c * 4);
#pragma unroll
        for (int i = 0; i < 8; ++i) {
            float4 t = wp[i];
            wv[i][0] = t.x; wv[i][1] = t.y; wv[i][2] = t.z; wv[i][3] = t.w;
        }
    }
#pragma unroll
    for (int k = 0; k < 4; ++k) {
        const int ll = l - 3 + k;
        if (ll >= 0) {
            short8 v = *(const short8*)(zx + (size_t)(row - 3 + k) * LDZX + DINNER + c);
#pragma unroll
            for (int i = 0; i < 8; ++i)
                acc[i] += bf2f((ushort_t)v[i]) * wv[i][k];
        }
    }
    short8 o;
#pragma unroll
    for (int i = 0; i < 8; ++i) {
        float s = acc[i] / (1.f + expf(-acc[i]));
        o[i] = (short)f2bf(s);
    }
    *(short8*)(convout + (size_t)row * DCONVD + c) = o;
}

// ---------------- Phase A (MFMA): per-chunk intra output + chunk state G ----------------
// dt = softplus(zx[.,4224+h] + bias) computed inline (dt kernel fused away).
__global__ __launch_bounds__(256) void chunk_intra_kernel(
    const ushort_t* __restrict__ cvb, const ushort_t* __restrict__ zx,
    const float* __restrict__ dt_bias,
    const float* __restrict__ A_log, const float* __restrict__ Dvec,
    ushort_t* __restrict__ ybuf, ushort_t* __restrict__ Gbuf,
    float* __restrict__ expPb)
{
    const int c = blockIdx.x, h = blockIdx.y, b = blockIdx.z;
    const int tid = threadIdx.x;
    const int wv = tid >> 6, lane = tid & 63;
    const int lr = lane & 15, lk = lane >> 4;

    __shared__ __align__(16) ushort_t Cs[4096];  // [t][n] swz
    __shared__ __align__(16) ushort_t Bs[4096];  // [t][n] swz
    __shared__ __align__(16) ushort_t Xt[4096];  // [p][t] swz
    __shared__ __align__(16) ushort_t Ss[4096];  // [i][j] swz (masked S, bf16)
    __shared__ __align__(16) ushort_t Bw[4096];  // [n][t] swz (B^T * w_t)
    __shared__ float sP[64], sdt[64], sWf[64];

    const int t4 = tid >> 2, qq = tid & 3;
    const size_t rowg0 = (size_t)b * L_SEQ + c * 64;
    const ushort_t* rowp = cvb + (rowg0 + t4) * DCONVD;

    short8 rb0 = *(const short8*)(rowp + DINNER + qq * 16);
    short8 rb1 = *(const short8*)(rowp + DINNER + qq * 16 + 8);
    short8 rc0 = *(const short8*)(rowp + DINNER + DSTATE + qq * 16);
    short8 rc1 = *(const short8*)(rowp + DINNER + DSTATE + qq * 16 + 8);
    short8 rx0 = *(const short8*)(rowp + h * 64 + qq * 16);
    short8 rx1 = *(const short8*)(rowp + h * 64 + qq * 16 + 8);

    *(short8*)&Cs[swzi(t4, qq * 16)]     = rc0;
    *(short8*)&Cs[swzi(t4, qq * 16 + 8)] = rc1;
    *(short8*)&Bs[swzi(t4, qq * 16)]     = rb0;
    *(short8*)&Bs[swzi(t4, qq * 16 + 8)] = rb1;
#pragma unroll
    for (int k = 0; k < 8; ++k) {
        Xt[swzi(qq * 16 + k, t4)]     = (ushort_t)rx0[k];
        Xt[swzi(qq * 16 + 8 + k, t4)] = (ushort_t)rx1[k];
    }
    if (tid < 64) {
        float dv = bf2f(zx[(rowg0 + tid) * LDZX + (NPROJ - NHEADS) + h]) + dt_bias[h];
        float dt = (dv > 20.f) ? dv : log1pf(expf(dv));
        float A = -__expf(A_log[h]);
        float P = dt * A;
#pragma unroll
        for (int off = 1; off < 64; off <<= 1) {
            float o = __shfl_up(P, off);
            if (tid >= off) P += o;
        }
        sP[tid] = P;
        sdt[tid] = dt;
        float P63 = __shfl(P, 63);
        sWf[tid] = __expf(P63 - P) * dt;
        expPb[(size_t)(b * NHEADS + h) * L_SEQ + c * 64 + tid] = __expf(P);
    }
    __syncthreads();

    {
        const float w = sWf[t4];
#pragma unroll
        for (int k = 0; k < 8; ++k) {
            Bw[swzi(qq * 16 + k, t4)]     = f2bf(bf2f((ushort_t)rb0[k]) * w);
            Bw[swzi(qq * 16 + 8 + k, t4)] = f2bf(bf2f((ushort_t)rb1[k]) * w);
        }
    }

    // ---- MFMA 1: S = C.B^T ----
    const float Dh = Dvec[h];
    {
        short8 a0 = *(const short8*)&Cs[swzi(wv * 16 + lr, lk * 8)];
        short8 a1 = *(const short8*)&Cs[swzi(wv * 16 + lr, 32 + lk * 8)];
        f32x4 acc[4];
        const f32x4 zero = {0.f, 0.f, 0.f, 0.f};
#pragma unroll
        for (int nj = 0; nj < 4; ++nj) {
            short8 b0 = *(const short8*)&Bs[swzi(nj * 16 + lr, lk * 8)];
            short8 b1 = *(const short8*)&Bs[swzi(nj * 16 + lr, 32 + lk * 8)];
            acc[nj] = __builtin_amdgcn_mfma_f32_16x16x32_bf16(a0, b0, zero, 0, 0, 0);
            acc[nj] = __builtin_amdgcn_mfma_f32_16x16x32_bf16(a1, b1, acc[nj], 0, 0, 0);
        }
#pragma unroll
        for (int r = 0; r < 4; ++r) {
            const int i = wv * 16 + lk * 4 + r;
            const float Pi = sP[i];
#pragma unroll
            for (int nj = 0; nj < 4; ++nj) {
                const int j = nj * 16 + lr;
                float s = 0.f;
                if (j <= i) s = acc[nj][r] * __expf(Pi - sP[j]) * sdt[j];
                if (j == i) s += Dh;
                Ss[swzi(i, j)] = f2bf(s);
            }
        }
    }
    __syncthreads();

    // ---- MFMA 2: Y = S.X -> ybuf ----
    {
        short8 a0 = *(const short8*)&Ss[swzi(wv * 16 + lr, lk * 8)];
        short8 a1 = *(const short8*)&Ss[swzi(wv * 16 + lr, 32 + lk * 8)];
        const f32x4 zero = {0.f, 0.f, 0.f, 0.f};
#pragma unroll
        for (int np = 0; np < 4; ++np) {
            short8 b0 = *(const short8*)&Xt[swzi(np * 16 + lr, lk * 8)];
            short8 b1 = *(const short8*)&Xt[swzi(np * 16 + lr, 32 + lk * 8)];
            f32x4 acc = __builtin_amdgcn_mfma_f32_16x16x32_bf16(a0, b0, zero, 0, 0, 0);
            acc = __builtin_amdgcn_mfma_f32_16x16x32_bf16(a1, b1, acc, 0, 0, 0);
#pragma unroll
            for (int r = 0; r < 4; ++r) {
                const int i = wv * 16 + lk * 4 + r;
                const int p = np * 16 + lr;
                ybuf[(rowg0 + i) * DINNER + (size_t)h * 64 + p] = f2bf(acc[r]);
            }
        }
    }

    // ---- MFMA 3: G^T[p][n] = Xt . Bw^T -> Gbuf ([p][n] layout) ----
    {
        short8 a0 = *(const short8*)&Xt[swzi(wv * 16 + lr, lk * 8)];
        short8 a1 = *(const short8*)&Xt[swzi(wv * 16 + lr, 32 + lk * 8)];
        const f32x4 zero = {0.f, 0.f, 0.f, 0.f};
        const size_t gbase = ((size_t)((b * NHEADS + h) * NCHUNK + c)) << 12;
#pragma unroll
        for (int nt = 0; nt < 4; ++nt) {
            short8 b0 = *(const short8*)&Bw[swzi(nt * 16 + lr, lk * 8)];
            short8 b1 = *(const short8*)&Bw[swzi(nt * 16 + lr, 32 + lk * 8)];
            f32x4 acc = __builtin_amdgcn_mfma_f32_16x16x32_bf16(a0, b0, zero, 0, 0, 0);
            acc = __builtin_amdgcn_mfma_f32_16x16x32_bf16(a1, b1, acc, 0, 0, 0);
#pragma unroll
            for (int r = 0; r < 4; ++r) {
                const int p = wv * 16 + lk * 4 + r;
                const int n = nt * 16 + lr;
                Gbuf[gbase + p * 64 + n] = f2bf(acc[r]);
            }
        }
    }
}

// ---------------- Phase B1: elementwise chunk-state scan (in-place G -> hstates) ----------------
__global__ __launch_bounds__(256) void state_scan_kernel(
    ushort_t* __restrict__ GH, const float* __restrict__ expPb)
{
    const int half = blockIdx.x, h = blockIdx.y, b = blockIdx.z;
    const int bh = b * NHEADS + h;
    const int e0 = half * 2048 + threadIdx.x * 8;
    ushort_t* base = GH + ((size_t)bh << 17);
    const float* ep = expPb + (size_t)bh * L_SEQ;

    float hr[8];
#pragma unroll
    for (int k = 0; k < 8; ++k) hr[k] = 0.f;

    short8 g = *(const short8*)(base + e0);
    float Ec = ep[63];
    for (int c = 0; c < NCHUNK; ++c) {
        short8 gn = g; float En = 0.f;
        if (c + 1 < NCHUNK) {
            gn = *(const short8*)(base + ((size_t)(c + 1) << 12) + e0);
            En = ep[(c + 1) * 64 + 63];
        }
        short8 o;
#pragma unroll
        for (int k = 0; k < 8; ++k) o[k] = (short)f2bf(hr[k]);
        *(short8*)(base + ((size_t)c << 12) + e0) = o;
#pragma unroll
        for (int k = 0; k < 8; ++k) hr[k] = hr[k] * Ec + bf2f((ushort_t)g[k]);
        g = gn; Ec = En;
    }
}

// ---------------- Phase B2 (MFMA): y_inter[t][p] = expP[t] * sum_n C[t][n] h[n][p] ----------------
__global__ __launch_bounds__(256) void y_inter_kernel(
    const ushort_t* __restrict__ cvb, const float* __restrict__ expPb,
    const ushort_t* __restrict__ hst, ushort_t* __restrict__ ybuf)
{
    const int c = blockIdx.x + 1, h = blockIdx.y, b = blockIdx.z;
    const int tid = threadIdx.x;
    const int wv = tid >> 6, lane = tid & 63;
    const int lr = lane & 15, lk = lane >> 4;
    const int bh = b * NHEADS + h;

    __shared__ __align__(16) ushort_t Cs[4096];  // [t][n] swz
    __shared__ __align__(16) ushort_t Hp[4096];  // [p][n] swz
    __shared__ float sEp[64];

    const int t4 = tid >> 2, qq = tid & 3;
    const size_t rowg0 = (size_t)b * L_SEQ + c * 64;
    {
        const ushort_t* rp = cvb + (rowg0 + t4) * DCONVD + DINNER + DSTATE + qq * 16;
        *(short8*)&Cs[swzi(t4, qq * 16)]     = *(const short8*)rp;
        *(short8*)&Cs[swzi(t4, qq * 16 + 8)] = *(const short8*)(rp + 8);
        const ushort_t* hr = hst + (((size_t)(bh * NCHUNK + c)) << 12) + t4 * 64 + qq * 16;
        *(short8*)&Hp[swzi(t4, qq * 16)]     = *(const short8*)hr;
        *(short8*)&Hp[swzi(t4, qq * 16 + 8)] = *(const short8*)(hr + 8);
    }
    if (tid < 64) sEp[tid] = expPb[(size_t)bh * L_SEQ + c * 64 + tid];
    __syncthreads();

    short8 a0 = *(const short8*)&Cs[swzi(wv * 16 + lr, lk * 8)];
    short8 a1 = *(const short8*)&Cs[swzi(wv * 16 + lr, 32 + lk * 8)];
    const f32x4 zero = {0.f, 0.f, 0.f, 0.f};
#pragma unroll
    for (int np = 0; np < 4; ++np) {
        short8 b0 = *(const short8*)&Hp[swzi(np * 16 + lr, lk * 8)];
        short8 b1 = *(const short8*)&Hp[swzi(np * 16 + lr, 32 + lk * 8)];
        f32x4 acc = __builtin_amdgcn_mfma_f32_16x16x32_bf16(a0, b0, zero, 0, 0, 0);
        acc = __builtin_amdgcn_mfma_f32_16x16x32_bf16(a1, b1, acc, 0, 0, 0);
#pragma unroll
        for (int r = 0; r < 4; ++r) {
            const int t = wv * 16 + lk * 4 + r;
            const int p = np * 16 + lr;
            ushort_t* yp = &ybuf[(rowg0 + t) * DINNER + (size_t)h * 64 + p];
            *yp = f2bf(bf2f(*yp) + acc[r] * sEp[t]);
        }
    }
}

// ---------------- gate (y * silu(z)) + RMSNorm -> bf16 ----------------
__global__ __launch_bounds__(256) void gatenorm_kernel(const ushort_t* __restrict__ ybuf,
                                                       const ushort_t* __restrict__ zx,
                                                       const float* __restrict__ norm_w,
                                                       ushort_t* __restrict__ gbuf) {
    const int row = blockIdx.x;
    const int tid = threadIdx.x;
    short8 yv = *(const short8*)(ybuf + (size_t)row * DINNER + tid * 8);
    short8 zv = *(const short8*)(zx + (size_t)row * LDZX + tid * 8);
    float g[8];
    float ss = 0.f;
#pragma unroll
    for (int i = 0; i < 8; ++i) {
        float y = bf2f((ushort_t)yv[i]);
        float z = bf2f((ushort_t)zv[i]);
        float sz = z / (1.f + expf(-z));
        float gg = y * sz;
        g[i] = gg;
        ss += gg * gg;
    }
#pragma unroll
    for (int o = 32; o > 0; o >>= 1) ss += __shfl_xor(ss, o);
    __shared__ float wsum[4];
    if ((tid & 63) == 0) wsum[tid >> 6] = ss;
    __syncthreads();
    float tot = wsum[0] + wsum[1] + wsum[2] + wsum[3];
    float scale = rsqrtf(tot * (1.0f / (float)DINNER) + 1e-5f);
    short8 o8;
#pragma unroll
    for (int i = 0; i < 8; ++i)
        o8[i] = (short)f2bf(g[i] * scale * norm_w[tid * 8 + i]);
    *(short8*)(gbuf + (size_t)row * DINNER + tid * 8) = o8;
}

// ---------------- launch ----------------
extern "C" void kernel_launch(void* const* d_in, const int* in_sizes, int n_in,
                              void* d_out, int out_size, void* d_ws, size_t ws_size,
                              hipStream_t stream) {
    const float* x          = (const float*)d_in[0];
    const float* in_proj_w  = (const float*)d_in[1];
    const float* conv_w     = (const float*)d_in[2];
    const float* conv_b     = (const float*)d_in[3];
    const float* dt_bias    = (const float*)d_in[4];
    const float* A_log      = (const float*)d_in[5];
    const float* Dvec       = (const float*)d_in[6];
    const float* norm_w     = (const float*)d_in[7];
    const float* out_proj_w = (const float*)d_in[8];
    float* out = (float*)d_out;

    char* ws = (char*)d_ws;
    size_t off = 0;
    ushort_t* owbf  = (ushort_t*)(ws + off); off += (size_t)KDIM * DINNER * 2;     // 4.2 MB
    ushort_t* zx    = (ushort_t*)(ws + off); off += (size_t)NROWS * LDZX * 2;      // 71.3 MB
    ushort_t* cvb   = (ushort_t*)(ws + off); off += (size_t)NROWS * DCONVD * 2;    // 35.7 MB
    float*    expPb = (float*)(ws + off);    off += (size_t)128 * L_SEQ * 4;       // 1.05 MB
    ushort_t* ybuf  = (ushort_t*)(ws + off); off += (size_t)NROWS * DINNER * 2;    // 33.6 MB
    char* tail = ws + off;
    ushort_t* xbf  = (ushort_t*)tail;
    ushort_t* wbf  = (ushort_t*)(tail + (size_t)NROWS * KDIM * 2);
    ushort_t* Gbuf = (ushort_t*)tail;
    ushort_t* gbuf = (ushort_t*)tail;

    // casts
    cast_bf16_kernel<<<8192, 256, 0, stream>>>(x, xbf, NROWS * KDIM / 4);
    cast_pad_w_kernel<<<4352, 256, 0, stream>>>(in_proj_w, wbf);
    cast_bf16_kernel<<<2048, 256, 0, stream>>>(out_proj_w, owbf, KDIM * DINNER / 4);

    // in-proj GEMM: zx[8192][4352] (bf16), 256x256 4-phase  (grid 544 = 8*68)
    gemm256_kernel<256, true><<<544, 512, 0, stream>>>(xbf, wbf, zx, KDIM, LDZX, 17);

    // conv + silu (short8-vectorized)
    conv_silu_kernel<<<NROWS * 272 / 256, 256, 0, stream>>>(zx, conv_w, conv_b, cvb);

    // chunked scan: phase A (parallel, MFMA; dt softplus fused)
    chunk_intra_kernel<<<dim3(NCHUNK, NHEADS, 4), 256, 0, stream>>>(
        cvb, zx, dt_bias, A_log, Dvec, ybuf, Gbuf, expPb);
    // phase B1: elementwise state scan (in-place G -> hstates)
    state_scan_kernel<<<dim3(2, NHEADS, 4), 256, 0, stream>>>(Gbuf, expPb);
    // phase B2: inter-chunk contribution (parallel MFMA matmuls)
    y_inter_kernel<<<dim3(NCHUNK - 1, NHEADS, 4), 256, 0, stream>>>(
        cvb, expPb, Gbuf, ybuf);

    // gate + rmsnorm
    gatenorm_kernel<<<NROWS, 256, 0, stream>>>(ybuf, zx, norm_w, gbuf);

    // out-proj GEMM -> d_out (f32), 256x128 4-phase  (grid 256 = 8*32, 1 round)
    gemm256_kernel<128, false><<<256, 512, 0, stream>>>(gbuf, owbf, out, DINNER, KDIM, 8);
}